// Round 1
// baseline (2332.549 us; speedup 1.0000x reference)
//
#include <hip/hip_runtime.h>
#include <cstddef>

#define NW 80000
#define ND 16000
#define EWW 200000
#define EWD 200000

// ---------- helpers: order-preserving float<->uint map for atomicMax ----------
__device__ __forceinline__ unsigned fmap(float f) {
    unsigned u = __float_as_uint(f);
    return (u & 0x80000000u) ? ~u : (u | 0x80000000u);
}
__device__ __forceinline__ float funmap(unsigned s) {
    return (s & 0x80000000u) ? __uint_as_float(s ^ 0x80000000u)
                             : __uint_as_float(~s);
}

// ---------- Wl/Wr = per-head contraction of W with al/ar:  [K,4] ----------
__global__ void make_wlr(const float* __restrict__ W, const float* __restrict__ al,
                         const float* __restrict__ ar, float* __restrict__ Wl,
                         float* __restrict__ Wr, int K) {
    int i = blockIdx.x * blockDim.x + threadIdx.x;
    if (i >= K * 4) return;
    int k = i >> 2, h = i & 3;
    float sl = 0.f, sr = 0.f;
    const float* wr = W + (size_t)k * 512 + h * 128;
    const float* alr = al + h * 128;
    const float* arr = ar + h * 128;
    for (int f = 0; f < 128; f++) {
        float w = wr[f];
        sl += w * alr[f];
        sr += w * arr[f];
    }
    Wl[k * 4 + h] = sl;
    Wr[k * 4 + h] = sr;
}

// ---------- el/er = x @ Wv  ([N,4]) ----------
__global__ void attn_logits(const float* __restrict__ x, const float* __restrict__ Wv,
                            float* __restrict__ out, int N, int K) {
    int i = blockIdx.x * blockDim.x + threadIdx.x;
    if (i >= N * 4) return;
    int n = i >> 2, h = i & 3;
    const float* xr = x + (size_t)n * K;
    float acc = 0.f;
    for (int k = 0; k < K; k++) acc += xr[k] * Wv[k * 4 + h];
    out[i] = acc;
}

// ---------- fp32 tiled GEMM: C[M,N] = A[M,K] @ B[K,N], 128x128 tile ----------
__global__ __launch_bounds__(256) void gemm_f32(const float* __restrict__ A,
                                                const float* __restrict__ B,
                                                float* __restrict__ C,
                                                int M, int N, int K) {
    __shared__ float As[16][132];   // transposed: As[k][m]
    __shared__ float Bs[16][128];
    int tid = threadIdx.x;
    int tx = tid & 15, ty = tid >> 4;
    int bm = blockIdx.y * 128, bn = blockIdx.x * 128;
    float acc[8][8] = {};
    for (int k0 = 0; k0 < K; k0 += 16) {
#pragma unroll
        for (int i = 0; i < 8; i++) {
            int idx = tid + i * 256;           // 0..2047 over 128 rows x 16 k
            int m = idx >> 4, kk = idx & 15;
            As[kk][m] = A[(size_t)(bm + m) * K + k0 + kk];
        }
#pragma unroll
        for (int i = 0; i < 8; i++) {
            int idx = tid + i * 256;           // 0..2047 over 16 k x 128 n
            int kk = idx >> 7, n = idx & 127;
            Bs[kk][n] = B[(size_t)(k0 + kk) * N + bn + n];
        }
        __syncthreads();
#pragma unroll
        for (int kk = 0; kk < 16; kk++) {
            float a[8], b[8];
#pragma unroll
            for (int i = 0; i < 8; i++) a[i] = As[kk][ty * 8 + i];
#pragma unroll
            for (int j = 0; j < 8; j++) b[j] = Bs[kk][tx * 8 + j];
#pragma unroll
            for (int i = 0; i < 8; i++)
#pragma unroll
                for (int j = 0; j < 8; j++) acc[i][j] += a[i] * b[j];
        }
        __syncthreads();
    }
    for (int i = 0; i < 8; i++) {
        float* cr = C + (size_t)(bm + ty * 8 + i) * N + bn;
#pragma unroll
        for (int j = 0; j < 8; j++) cr[tx * 8 + j] = acc[i][j];
    }
}

// ---------- hout init = per-feature head-sum of bias ----------
__global__ void init_hout(float* __restrict__ h, const float* __restrict__ b, int n) {
    int i = blockIdx.x * blockDim.x + threadIdx.x;
    if (i >= n) return;
    int f = i & 127;
    h[i] = b[f] + b[128 + f] + b[256 + f] + b[384 + f];
}

// ---------- edge pass 1: logits + segment max ----------
__global__ void edge_logits(const int* __restrict__ src, const int* __restrict__ dst,
                            const float* __restrict__ el, const float* __restrict__ er,
                            float* __restrict__ e, unsigned* __restrict__ mmax, int E) {
    int t = blockIdx.x * blockDim.x + threadIdx.x;
    if (t >= E) return;
    int s = src[t], d = dst[t];
#pragma unroll
    for (int h = 0; h < 4; h++) {
        float v = el[s * 4 + h] + er[d * 4 + h];
        v = v > 0.f ? v : 0.2f * v;   // leaky_relu(0.2)
        e[t * 4 + h] = v;
        atomicMax(&mmax[d * 4 + h], fmap(v));
    }
}

// ---------- edge pass 2: exp + segment sum ----------
__global__ void edge_expsum(const int* __restrict__ dst, float* __restrict__ e,
                            const unsigned* __restrict__ mmax, float* __restrict__ ssum,
                            int E) {
    int t = blockIdx.x * blockDim.x + threadIdx.x;
    if (t >= E) return;
    int d = dst[t];
#pragma unroll
    for (int h = 0; h < 4; h++) {
        float v = expf(e[t * 4 + h] - funmap(mmax[d * 4 + h]));
        e[t * 4 + h] = v;
        atomicAdd(&ssum[d * 4 + h], v);
    }
}

// ---------- edge pass 3: alpha-weighted scatter, head-sum fused ----------
// 2 edges per 256-thread block; thread f handles one of 128 features.
__global__ void edge_scatter(const int* __restrict__ src, const int* __restrict__ dst,
                             const float* __restrict__ ex, const float* __restrict__ ssum,
                             const float* __restrict__ z, float* __restrict__ hout, int E) {
    int eid = blockIdx.x * 2 + (threadIdx.x >> 7);
    int f = threadIdx.x & 127;
    if (eid >= E) return;
    int s = src[eid], d = dst[eid];
    float a0 = ex[eid * 4 + 0] / ssum[d * 4 + 0];
    float a1 = ex[eid * 4 + 1] / ssum[d * 4 + 1];
    float a2 = ex[eid * 4 + 2] / ssum[d * 4 + 2];
    float a3 = ex[eid * 4 + 3] / ssum[d * 4 + 3];
    const float* zr = z + (size_t)s * 512;
    float v = a0 * zr[f] + a1 * zr[128 + f] + a2 * zr[256 + f] + a3 * zr[384 + f];
    atomicAdd(&hout[(size_t)d * 128 + f], v);
}

// ---------- relu in place ----------
__global__ void relu_ip(float* __restrict__ x, int n) {
    int i = blockIdx.x * blockDim.x + threadIdx.x;
    if (i < n) x[i] = fmaxf(x[i], 0.f);
}

// ---------- one relation-layer ----------
static void run_rel(const float* x_src, int Ns, const float* x_dst, int Nd,
                    const int* src, const int* dst, int E,
                    const float* W, const float* al, const float* ar, const float* b,
                    int K, float* hout,
                    float* z, float* el, float* er, float* ebuf, float* ssum,
                    unsigned* mmax, float* Wl, float* Wr, hipStream_t stream) {
    make_wlr<<<(K * 4 + 255) / 256, 256, 0, stream>>>(W, al, ar, Wl, Wr, K);
    gemm_f32<<<dim3(512 / 128, Ns / 128), 256, 0, stream>>>(x_src, W, z, Ns, 512, K);
    attn_logits<<<(Ns * 4 + 255) / 256, 256, 0, stream>>>(x_src, Wl, el, Ns, K);
    attn_logits<<<(Nd * 4 + 255) / 256, 256, 0, stream>>>(x_dst, Wr, er, Nd, K);
    hipMemsetAsync(mmax, 0, (size_t)Nd * 4 * sizeof(unsigned), stream);
    hipMemsetAsync(ssum, 0, (size_t)Nd * 4 * sizeof(float), stream);
    init_hout<<<(Nd * 128 + 255) / 256, 256, 0, stream>>>(hout, b, Nd * 128);
    edge_logits<<<(E + 255) / 256, 256, 0, stream>>>(src, dst, el, er, ebuf, mmax, E);
    edge_expsum<<<(E + 255) / 256, 256, 0, stream>>>(dst, ebuf, mmax, ssum, E);
    edge_scatter<<<(E + 1) / 2, 256, 0, stream>>>(src, dst, ebuf, ssum, z, hout, E);
}

extern "C" void kernel_launch(void* const* d_in, const int* in_sizes, int n_in,
                              void* d_out, int out_size, void* d_ws, size_t ws_size,
                              hipStream_t stream) {
    const float* xw     = (const float*)d_in[0];
    const float* xd     = (const float*)d_in[1];
    const float* W_ww0  = (const float*)d_in[2];
    const float* al_ww0 = (const float*)d_in[3];
    const float* ar_ww0 = (const float*)d_in[4];
    const float* b_ww0  = (const float*)d_in[5];
    const float* W_wd0  = (const float*)d_in[6];
    const float* al_wd0 = (const float*)d_in[7];
    const float* ar_wd0 = (const float*)d_in[8];
    const float* b_wd0  = (const float*)d_in[9];
    const float* W_ww1  = (const float*)d_in[10];
    const float* al_ww1 = (const float*)d_in[11];
    const float* ar_ww1 = (const float*)d_in[12];
    const float* b_ww1  = (const float*)d_in[13];
    const float* W_wd1  = (const float*)d_in[14];
    const float* al_wd1 = (const float*)d_in[15];
    const float* ar_wd1 = (const float*)d_in[16];
    const float* b_wd1  = (const float*)d_in[17];
    const int* ww_src   = (const int*)d_in[18];
    const int* ww_dst   = (const int*)d_in[19];
    const int* wd_src   = (const int*)d_in[20];
    const int* wd_dst   = (const int*)d_in[21];

    // ---- workspace carve (floats) ----
    float* ws = (float*)d_ws;
    float* z     = ws;                       // 80000*512  = 40,960,000
    float* el    = z + (size_t)NW * 512;     // 320,000
    float* er    = el + (size_t)NW * 4;      // 320,000 (max of NW,ND sides)
    float* ebuf  = er + (size_t)NW * 4;      // 800,000
    float* ssum  = ebuf + (size_t)EWW * 4;   // 320,000
    unsigned* mm = (unsigned*)(ssum + (size_t)NW * 4);  // 320,000
    float* Wl    = (float*)(mm + (size_t)NW * 4);       // 1024
    float* Wr    = Wl + 1024;                            // 1024
    float* xw1   = Wr + 1024;                // 10,240,000
    float* xd1   = xw1 + (size_t)NW * 128;   // 2,048,000

    float* out_xw = (float*)d_out;
    float* out_xd = out_xw + (size_t)NW * 128;

    // ---- layer 0 (K=256): hw <- ww(xw,xw), hd <- wd(xw,xd) ----
    run_rel(xw, NW, xw, NW, ww_src, ww_dst, EWW, W_ww0, al_ww0, ar_ww0, b_ww0,
            256, xw1, z, el, er, ebuf, ssum, mm, Wl, Wr, stream);
    run_rel(xw, NW, xd, ND, wd_src, wd_dst, EWD, W_wd0, al_wd0, ar_wd0, b_wd0,
            256, xd1, z, el, er, ebuf, ssum, mm, Wl, Wr, stream);
    relu_ip<<<(NW * 128 + 255) / 256, 256, 0, stream>>>(xw1, NW * 128);
    relu_ip<<<(ND * 128 + 255) / 256, 256, 0, stream>>>(xd1, ND * 128);

    // ---- layer 1 (K=128): accumulate straight into d_out, relu in place ----
    run_rel(xw1, NW, xw1, NW, ww_src, ww_dst, EWW, W_ww1, al_ww1, ar_ww1, b_ww1,
            128, out_xw, z, el, er, ebuf, ssum, mm, Wl, Wr, stream);
    run_rel(xw1, NW, xd1, ND, wd_src, wd_dst, EWD, W_wd1, al_wd1, ar_wd1, b_wd1,
            128, out_xd, z, el, er, ebuf, ssum, mm, Wl, Wr, stream);
    relu_ip<<<(NW * 128 + 255) / 256, 256, 0, stream>>>(out_xw, NW * 128);
    relu_ip<<<(ND * 128 + 255) / 256, 256, 0, stream>>>(out_xd, ND * 128);
}

// Round 2
// 1367.848 us; speedup vs baseline: 1.7053x; 1.7053x over previous
//
#include <hip/hip_runtime.h>
#include <hip/hip_bf16.h>
#include <cstddef>

#define NW 80000
#define ND 16000
#define EWW 200000
#define EWD 200000

typedef short v8s __attribute__((ext_vector_type(8)));
typedef float v4f __attribute__((ext_vector_type(4)));

// ---------- helpers: order-preserving float<->uint map for atomicMax ----------
__device__ __forceinline__ unsigned fmap(float f) {
    unsigned u = __float_as_uint(f);
    return (u & 0x80000000u) ? ~u : (u | 0x80000000u);
}
__device__ __forceinline__ float funmap(unsigned s) {
    return (s & 0x80000000u) ? __uint_as_float(s ^ 0x80000000u)
                             : __uint_as_float(~s);
}

// ---------- fp32 -> bf16 cast ----------
__global__ void cast_bf16(const float* __restrict__ x, __hip_bfloat16* __restrict__ xb, int n) {
    int i = blockIdx.x * blockDim.x + threadIdx.x;
    if (i < n) xb[i] = __float2bfloat16(x[i]);
}

// ---------- W[K,512] -> Wt[512,K] bf16 ----------
__global__ void transpose_w(const float* __restrict__ W, __hip_bfloat16* __restrict__ Wt, int K) {
    int i = blockIdx.x * blockDim.x + threadIdx.x;
    if (i >= 512 * K) return;
    int n = i / K, k = i - n * K;
    Wt[i] = __float2bfloat16(W[k * 512 + n]);
}

// ---------- Wl/Wr = per-head contraction of W with al/ar:  [K,4] ----------
__global__ void make_wlr(const float* __restrict__ W, const float* __restrict__ al,
                         const float* __restrict__ ar, float* __restrict__ Wl,
                         float* __restrict__ Wr, int K) {
    int i = blockIdx.x * blockDim.x + threadIdx.x;
    if (i >= K * 4) return;
    int k = i >> 2, h = i & 3;
    float sl = 0.f, sr = 0.f;
    const float* wr = W + (size_t)k * 512 + h * 128;
    const float* alr = al + h * 128;
    const float* arr = ar + h * 128;
    for (int f = 0; f < 128; f++) {
        float w = wr[f];
        sl += w * alr[f];
        sr += w * arr[f];
    }
    Wl[k * 4 + h] = sl;
    Wr[k * 4 + h] = sr;
}

// ---------- el/er = x @ Wv ([N,4]); one wave per row, coalesced ----------
__global__ __launch_bounds__(256) void attn_logits(const float* __restrict__ x,
                                                   const float* __restrict__ Wv,
                                                   float* __restrict__ out, int N, int K) {
    int wave = threadIdx.x >> 6, lane = threadIdx.x & 63;
    int row = blockIdx.x * 4 + wave;
    if (row >= N) return;
    const float* xr = x + (size_t)row * K;
    float a0 = 0.f, a1 = 0.f, a2 = 0.f, a3 = 0.f;
    for (int k = lane; k < K; k += 64) {
        float v = xr[k];
        const float* w = Wv + k * 4;
        a0 += v * w[0]; a1 += v * w[1]; a2 += v * w[2]; a3 += v * w[3];
    }
#pragma unroll
    for (int off = 32; off; off >>= 1) {
        a0 += __shfl_down(a0, off);
        a1 += __shfl_down(a1, off);
        a2 += __shfl_down(a2, off);
        a3 += __shfl_down(a3, off);
    }
    if (lane == 0) {
        out[row * 4 + 0] = a0; out[row * 4 + 1] = a1;
        out[row * 4 + 2] = a2; out[row * 4 + 3] = a3;
    }
}

// ---------- bf16 MFMA GEMM: C[M,N] = A[M,K] @ B[K,N]; Bt = B^T [N,K] ----------
// BM=BN=128, BK=32; 4 waves, wave w does rows w*32..w*32+31 x all 128 cols.
__global__ __launch_bounds__(256) void gemm_bf16(const __hip_bfloat16* __restrict__ A,
                                                 const __hip_bfloat16* __restrict__ Bt,
                                                 __hip_bfloat16* __restrict__ C,
                                                 int M, int N, int K) {
    __shared__ short As[128][40];   // pad 32->40: 80B row stride, 16B-aligned b128 reads
    __shared__ short Bs[128][40];
    int tid = threadIdx.x;
    int wave = tid >> 6, lane = tid & 63;
    int l16 = lane & 15, quad = lane >> 4;
    int bm = blockIdx.y * 128, bn = blockIdx.x * 128;
    v4f acc[2][8] = {};
    int r = tid >> 2, ko = (tid & 3) * 8;
    for (int k0 = 0; k0 < K; k0 += 32) {
        *(uint4*)&As[r][ko]      = *(const uint4*)&A[(size_t)(bm + r) * K + k0 + ko];
        *(uint4*)&As[r + 64][ko] = *(const uint4*)&A[(size_t)(bm + r + 64) * K + k0 + ko];
        *(uint4*)&Bs[r][ko]      = *(const uint4*)&Bt[(size_t)(bn + r) * K + k0 + ko];
        *(uint4*)&Bs[r + 64][ko] = *(const uint4*)&Bt[(size_t)(bn + r + 64) * K + k0 + ko];
        __syncthreads();
        v8s a[2], b[8];
#pragma unroll
        for (int rr = 0; rr < 2; rr++) a[rr] = *(v8s*)&As[wave * 32 + rr * 16 + l16][quad * 8];
#pragma unroll
        for (int c = 0; c < 8; c++) b[c] = *(v8s*)&Bs[c * 16 + l16][quad * 8];
#pragma unroll
        for (int rr = 0; rr < 2; rr++)
#pragma unroll
            for (int c = 0; c < 8; c++)
                acc[rr][c] = __builtin_amdgcn_mfma_f32_16x16x32_bf16(a[rr], b[c], acc[rr][c], 0, 0, 0);
        __syncthreads();
    }
#pragma unroll
    for (int rr = 0; rr < 2; rr++)
#pragma unroll
        for (int c = 0; c < 8; c++)
#pragma unroll
            for (int i = 0; i < 4; i++) {
                int row = bm + wave * 32 + rr * 16 + quad * 4 + i;
                int col = bn + c * 16 + l16;
                C[(size_t)row * N + col] = __float2bfloat16(acc[rr][c][i]);
            }
}

// ---------- hout init = per-feature head-sum of bias ----------
__global__ void init_hout(float* __restrict__ h, const float* __restrict__ b, int n) {
    int i = blockIdx.x * blockDim.x + threadIdx.x;
    if (i >= n) return;
    int f = i & 127;
    h[i] = b[f] + b[128 + f] + b[256 + f] + b[384 + f];
}

// ---------- edge pass 1: logits + segment max ----------
__global__ void edge_logits(const int* __restrict__ src, const int* __restrict__ dst,
                            const float* __restrict__ el, const float* __restrict__ er,
                            float* __restrict__ e, unsigned* __restrict__ mmax, int E) {
    int t = blockIdx.x * blockDim.x + threadIdx.x;
    if (t >= E) return;
    int s = src[t], d = dst[t];
#pragma unroll
    for (int h = 0; h < 4; h++) {
        float v = el[s * 4 + h] + er[d * 4 + h];
        v = v > 0.f ? v : 0.2f * v;   // leaky_relu(0.2)
        e[t * 4 + h] = v;
        atomicMax(&mmax[d * 4 + h], fmap(v));
    }
}

// ---------- edge pass 2: exp + segment sum ----------
__global__ void edge_expsum(const int* __restrict__ dst, float* __restrict__ e,
                            const unsigned* __restrict__ mmax, float* __restrict__ ssum,
                            int E) {
    int t = blockIdx.x * blockDim.x + threadIdx.x;
    if (t >= E) return;
    int d = dst[t];
#pragma unroll
    for (int h = 0; h < 4; h++) {
        float v = expf(e[t * 4 + h] - funmap(mmax[d * 4 + h]));
        e[t * 4 + h] = v;
        atomicAdd(&ssum[d * 4 + h], v);
    }
}

// ---------- edge pass 3: alpha-weighted scatter (z in bf16), head-sum fused ----------
__global__ void edge_scatter(const int* __restrict__ src, const int* __restrict__ dst,
                             const float* __restrict__ ex, const float* __restrict__ ssum,
                             const __hip_bfloat16* __restrict__ z, float* __restrict__ hout,
                             int E) {
    int eid = blockIdx.x * 2 + (threadIdx.x >> 7);
    int f = threadIdx.x & 127;
    if (eid >= E) return;
    int s = src[eid], d = dst[eid];
    float a0 = ex[eid * 4 + 0] / ssum[d * 4 + 0];
    float a1 = ex[eid * 4 + 1] / ssum[d * 4 + 1];
    float a2 = ex[eid * 4 + 2] / ssum[d * 4 + 2];
    float a3 = ex[eid * 4 + 3] / ssum[d * 4 + 3];
    const __hip_bfloat16* zr = z + (size_t)s * 512;
    float v = a0 * __bfloat162float(zr[f])       + a1 * __bfloat162float(zr[128 + f])
            + a2 * __bfloat162float(zr[256 + f]) + a3 * __bfloat162float(zr[384 + f]);
    atomicAdd(&hout[(size_t)d * 128 + f], v);
}

// ---------- relu in place ----------
__global__ void relu_ip(float* __restrict__ x, int n) {
    int i = blockIdx.x * blockDim.x + threadIdx.x;
    if (i < n) x[i] = fmaxf(x[i], 0.f);
}

// ---------- relu in place + bf16 copy ----------
__global__ void relu_cast(float* __restrict__ x, __hip_bfloat16* __restrict__ xb, int n) {
    int i = blockIdx.x * blockDim.x + threadIdx.x;
    if (i >= n) return;
    float v = fmaxf(x[i], 0.f);
    x[i] = v;
    xb[i] = __float2bfloat16(v);
}

// ---------- one relation-layer ----------
static void run_rel(const __hip_bfloat16* xsb, const float* x_src, int Ns,
                    const float* x_dst, int Nd,
                    const int* src, const int* dst, int E,
                    const float* W, const float* al, const float* ar, const float* b,
                    int K, float* hout,
                    __hip_bfloat16* z, __hip_bfloat16* Wt,
                    float* el, float* er, float* ebuf, float* ssum,
                    unsigned* mmax, float* Wl, float* Wr, hipStream_t stream) {
    transpose_w<<<(512 * K + 255) / 256, 256, 0, stream>>>(W, Wt, K);
    make_wlr<<<(K * 4 + 255) / 256, 256, 0, stream>>>(W, al, ar, Wl, Wr, K);
    gemm_bf16<<<dim3(512 / 128, Ns / 128), 256, 0, stream>>>(xsb, Wt, z, Ns, 512, K);
    attn_logits<<<(Ns + 3) / 4, 256, 0, stream>>>(x_src, Wl, el, Ns, K);
    attn_logits<<<(Nd + 3) / 4, 256, 0, stream>>>(x_dst, Wr, er, Nd, K);
    hipMemsetAsync(mmax, 0, (size_t)Nd * 4 * sizeof(unsigned), stream);
    hipMemsetAsync(ssum, 0, (size_t)Nd * 4 * sizeof(float), stream);
    init_hout<<<(Nd * 128 + 255) / 256, 256, 0, stream>>>(hout, b, Nd * 128);
    edge_logits<<<(E + 255) / 256, 256, 0, stream>>>(src, dst, el, er, ebuf, mmax, E);
    edge_expsum<<<(E + 255) / 256, 256, 0, stream>>>(dst, ebuf, mmax, ssum, E);
    edge_scatter<<<(E + 1) / 2, 256, 0, stream>>>(src, dst, ebuf, ssum, z, hout, E);
}

extern "C" void kernel_launch(void* const* d_in, const int* in_sizes, int n_in,
                              void* d_out, int out_size, void* d_ws, size_t ws_size,
                              hipStream_t stream) {
    const float* xw     = (const float*)d_in[0];
    const float* xd     = (const float*)d_in[1];
    const float* W_ww0  = (const float*)d_in[2];
    const float* al_ww0 = (const float*)d_in[3];
    const float* ar_ww0 = (const float*)d_in[4];
    const float* b_ww0  = (const float*)d_in[5];
    const float* W_wd0  = (const float*)d_in[6];
    const float* al_wd0 = (const float*)d_in[7];
    const float* ar_wd0 = (const float*)d_in[8];
    const float* b_wd0  = (const float*)d_in[9];
    const float* W_ww1  = (const float*)d_in[10];
    const float* al_ww1 = (const float*)d_in[11];
    const float* ar_ww1 = (const float*)d_in[12];
    const float* b_ww1  = (const float*)d_in[13];
    const float* W_wd1  = (const float*)d_in[14];
    const float* al_wd1 = (const float*)d_in[15];
    const float* ar_wd1 = (const float*)d_in[16];
    const float* b_wd1  = (const float*)d_in[17];
    const int* ww_src   = (const int*)d_in[18];
    const int* ww_dst   = (const int*)d_in[19];
    const int* wd_src   = (const int*)d_in[20];
    const int* wd_dst   = (const int*)d_in[21];

    // ---- workspace carve (bytes, all chunks 256B-aligned sizes) ----
    char* p = (char*)d_ws;
    __hip_bfloat16* z    = (__hip_bfloat16*)p; p += (size_t)NW * 512 * 2;   // 82 MB
    __hip_bfloat16* xwb  = (__hip_bfloat16*)p; p += (size_t)NW * 256 * 2;   // 41 MB
    __hip_bfloat16* xw1b = (__hip_bfloat16*)p; p += (size_t)NW * 128 * 2;   // 20.5 MB
    __hip_bfloat16* Wt   = (__hip_bfloat16*)p; p += (size_t)512 * 256 * 2;  // 256 KB
    float* el    = (float*)p; p += (size_t)NW * 4 * 4;
    float* er    = (float*)p; p += (size_t)NW * 4 * 4;
    float* ebuf  = (float*)p; p += (size_t)EWW * 4 * 4;
    float* ssum  = (float*)p; p += (size_t)NW * 4 * 4;
    unsigned* mm = (unsigned*)p; p += (size_t)NW * 4 * 4;
    float* Wl    = (float*)p; p += 4096;
    float* Wr    = (float*)p; p += 4096;
    float* xw1   = (float*)p; p += (size_t)NW * 128 * 4;  // 41 MB
    float* xd1   = (float*)p; p += (size_t)ND * 128 * 4;  // 8 MB

    float* out_xw = (float*)d_out;
    float* out_xd = out_xw + (size_t)NW * 128;

    // ---- layer 0 (K=256) ----
    cast_bf16<<<(NW * 256 + 255) / 256, 256, 0, stream>>>(xw, xwb, NW * 256);
    run_rel(xwb, xw, NW, xw, NW, ww_src, ww_dst, EWW, W_ww0, al_ww0, ar_ww0, b_ww0,
            256, xw1, z, Wt, el, er, ebuf, ssum, mm, Wl, Wr, stream);
    run_rel(xwb, xw, NW, xd, ND, wd_src, wd_dst, EWD, W_wd0, al_wd0, ar_wd0, b_wd0,
            256, xd1, z, Wt, el, er, ebuf, ssum, mm, Wl, Wr, stream);
    relu_cast<<<(NW * 128 + 255) / 256, 256, 0, stream>>>(xw1, xw1b, NW * 128);
    relu_ip<<<(ND * 128 + 255) / 256, 256, 0, stream>>>(xd1, ND * 128);

    // ---- layer 1 (K=128): accumulate straight into d_out, relu in place ----
    run_rel(xw1b, xw1, NW, xw1, NW, ww_src, ww_dst, EWW, W_ww1, al_ww1, ar_ww1, b_ww1,
            128, out_xw, z, Wt, el, er, ebuf, ssum, mm, Wl, Wr, stream);
    run_rel(xw1b, xw1, NW, xd1, ND, wd_src, wd_dst, EWD, W_wd1, al_wd1, ar_wd1, b_wd1,
            128, out_xd, z, Wt, el, er, ebuf, ssum, mm, Wl, Wr, stream);
    relu_ip<<<(NW * 128 + 255) / 256, 256, 0, stream>>>(out_xw, NW * 128);
    relu_ip<<<(ND * 128 + 255) / 256, 256, 0, stream>>>(out_xd, ND * 128);
}

// Round 3
// 817.237 us; speedup vs baseline: 2.8542x; 1.6737x over previous
//
#include <hip/hip_runtime.h>
#include <hip/hip_bf16.h>
#include <cstddef>
#include <cfloat>

#define NW 80000
#define ND 16000
#define EWW 200000
#define EWD 200000

typedef short v8s __attribute__((ext_vector_type(8)));
typedef float v4f __attribute__((ext_vector_type(4)));

static __device__ __forceinline__ float blo(unsigned u) { return __uint_as_float(u << 16); }
static __device__ __forceinline__ float bhi(unsigned u) { return __uint_as_float(u & 0xffff0000u); }

// ---------- fp32 -> bf16 cast, x4 vectorized ----------
__global__ void cast_bf16_v4(const float4* __restrict__ x, uint2* __restrict__ xb, int n4) {
    int i = blockIdx.x * blockDim.x + threadIdx.x;
    if (i >= n4) return;
    float4 v = x[i];
    __hip_bfloat162 a, b;
    a.x = __float2bfloat16(v.x); a.y = __float2bfloat16(v.y);
    b.x = __float2bfloat16(v.z); b.y = __float2bfloat16(v.w);
    uint2 o;
    o.x = *(unsigned*)&a; o.y = *(unsigned*)&b;
    xb[i] = o;
}

// ---------- W[K,512] -> Wt[512,K] bf16 ----------
__global__ void transpose_w(const float* __restrict__ W, __hip_bfloat16* __restrict__ Wt, int K) {
    int i = blockIdx.x * blockDim.x + threadIdx.x;
    if (i >= 512 * K) return;
    int n = i / K, k = i - n * K;
    Wt[i] = __float2bfloat16(W[k * 512 + n]);
}

// ---------- Wr = per-head contraction of W with ar: [K,4] (dst side of wd) ----------
__global__ void make_wr(const float* __restrict__ W, const float* __restrict__ ar,
                        float* __restrict__ Wr, int K) {
    int i = blockIdx.x * blockDim.x + threadIdx.x;
    if (i >= K * 4) return;
    int k = i >> 2, h = i & 3;
    float sr = 0.f;
    const float* wr = W + (size_t)k * 512 + h * 128;
    const float* arr = ar + h * 128;
    for (int f = 0; f < 128; f++) sr += wr[f] * arr[f];
    Wr[k * 4 + h] = sr;
}

// ---------- er = x @ Wr ([N,4]); one wave per row; fp32 x ----------
__global__ __launch_bounds__(256) void attn_f32(const float* __restrict__ x,
                                                const float* __restrict__ Wv,
                                                float* __restrict__ out, int N, int K) {
    int wave = threadIdx.x >> 6, lane = threadIdx.x & 63;
    int row = blockIdx.x * 4 + wave;
    if (row >= N) return;
    const float* xr = x + (size_t)row * K;
    float a0 = 0.f, a1 = 0.f, a2 = 0.f, a3 = 0.f;
    for (int k = lane; k < K; k += 64) {
        float v = xr[k];
        const float* w = Wv + k * 4;
        a0 += v * w[0]; a1 += v * w[1]; a2 += v * w[2]; a3 += v * w[3];
    }
#pragma unroll
    for (int off = 32; off; off >>= 1) {
        a0 += __shfl_down(a0, off); a1 += __shfl_down(a1, off);
        a2 += __shfl_down(a2, off); a3 += __shfl_down(a3, off);
    }
    if (lane == 0) {
        out[row * 4 + 0] = a0; out[row * 4 + 1] = a1;
        out[row * 4 + 2] = a2; out[row * 4 + 3] = a3;
    }
}

// ---------- bf16-x variant ----------
__global__ __launch_bounds__(256) void attn_bf16(const __hip_bfloat16* __restrict__ x,
                                                 const float* __restrict__ Wv,
                                                 float* __restrict__ out, int N, int K) {
    int wave = threadIdx.x >> 6, lane = threadIdx.x & 63;
    int row = blockIdx.x * 4 + wave;
    if (row >= N) return;
    const __hip_bfloat16* xr = x + (size_t)row * K;
    float a0 = 0.f, a1 = 0.f, a2 = 0.f, a3 = 0.f;
    for (int k = lane; k < K; k += 64) {
        float v = __bfloat162float(xr[k]);
        const float* w = Wv + k * 4;
        a0 += v * w[0]; a1 += v * w[1]; a2 += v * w[2]; a3 += v * w[3];
    }
#pragma unroll
    for (int off = 32; off; off >>= 1) {
        a0 += __shfl_down(a0, off); a1 += __shfl_down(a1, off);
        a2 += __shfl_down(a2, off); a3 += __shfl_down(a3, off);
    }
    if (lane == 0) {
        out[row * 4 + 0] = a0; out[row * 4 + 1] = a1;
        out[row * 4 + 2] = a2; out[row * 4 + 3] = a3;
    }
}

// ---------- bf16 MFMA GEMM + attention-logit epilogue ----------
// C[M,512] = A[M,K] @ B[K,512] (Bt = B^T).  BM=BN=128, BK=32; blockIdx.x = head h.
// Epilogue: el[row,h] = sum_f z[row,h*128+f]*al[h,f]; er likewise (if er != null).
__global__ __launch_bounds__(256) void gemm_epi(const __hip_bfloat16* __restrict__ A,
                                                const __hip_bfloat16* __restrict__ Bt,
                                                __hip_bfloat16* __restrict__ C,
                                                const float* __restrict__ al,
                                                const float* __restrict__ ar,
                                                float* __restrict__ el,
                                                float* __restrict__ er,
                                                int M, int K) {
    const int N = 512;
    __shared__ short As[128][40];   // pad 32->40: 80B row stride
    __shared__ short Bs[128][40];
    int tid = threadIdx.x;
    int wave = tid >> 6, lane = tid & 63;
    int l16 = lane & 15, quad = lane >> 4;
    int h = blockIdx.x;
    int bm = blockIdx.y * 128, bn = h * 128;
    v4f acc[2][8] = {};
    int r = tid >> 2, ko = (tid & 3) * 8;
    for (int k0 = 0; k0 < K; k0 += 32) {
        *(uint4*)&As[r][ko]      = *(const uint4*)&A[(size_t)(bm + r) * K + k0 + ko];
        *(uint4*)&As[r + 64][ko] = *(const uint4*)&A[(size_t)(bm + r + 64) * K + k0 + ko];
        *(uint4*)&Bs[r][ko]      = *(const uint4*)&Bt[(size_t)(bn + r) * K + k0 + ko];
        *(uint4*)&Bs[r + 64][ko] = *(const uint4*)&Bt[(size_t)(bn + r + 64) * K + k0 + ko];
        __syncthreads();
        v8s a[2], b[8];
#pragma unroll
        for (int rr = 0; rr < 2; rr++) a[rr] = *(v8s*)&As[wave * 32 + rr * 16 + l16][quad * 8];
#pragma unroll
        for (int c = 0; c < 8; c++) b[c] = *(v8s*)&Bs[c * 16 + l16][quad * 8];
#pragma unroll
        for (int rr = 0; rr < 2; rr++)
#pragma unroll
            for (int c = 0; c < 8; c++)
                acc[rr][c] = __builtin_amdgcn_mfma_f32_16x16x32_bf16(a[rr], b[c], acc[rr][c], 0, 0, 0);
        __syncthreads();
    }
    // store z (bf16)
#pragma unroll
    for (int rr = 0; rr < 2; rr++)
#pragma unroll
        for (int c = 0; c < 8; c++)
#pragma unroll
            for (int i = 0; i < 4; i++) {
                int row = bm + wave * 32 + rr * 16 + quad * 4 + i;
                int col = bn + c * 16 + l16;
                C[(size_t)row * N + col] = __float2bfloat16(acc[rr][c][i]);
            }
    // epilogue: el/er via per-lane dot + 16-lane shuffle reduce
    float alv[8], arv[8];
#pragma unroll
    for (int c = 0; c < 8; c++) {
        alv[c] = al[h * 128 + c * 16 + l16];
        arv[c] = ar[h * 128 + c * 16 + l16];
    }
#pragma unroll
    for (int rr = 0; rr < 2; rr++)
#pragma unroll
        for (int i = 0; i < 4; i++) {
            float pl = 0.f, pr = 0.f;
#pragma unroll
            for (int c = 0; c < 8; c++) {
                pl += acc[rr][c][i] * alv[c];
                pr += acc[rr][c][i] * arv[c];
            }
#pragma unroll
            for (int off = 1; off < 16; off <<= 1) {
                pl += __shfl_xor(pl, off);
                pr += __shfl_xor(pr, off);
            }
            if (l16 == 0) {
                int row = bm + wave * 32 + rr * 16 + quad * 4 + i;
                el[(size_t)row * 4 + h] = pl;
                if (er) er[(size_t)row * 4 + h] = pr;
            }
        }
}

// ---------- CSR build ----------
__global__ void hist_k(const int* __restrict__ dst, int* __restrict__ deg, int E) {
    int t = blockIdx.x * blockDim.x + threadIdx.x;
    if (t < E) atomicAdd(&deg[dst[t]], 1);
}

__global__ __launch_bounds__(1024) void scan_deg(const int* __restrict__ deg,
                                                 int* __restrict__ rp, int Nd, int E) {
    __shared__ int ts[1024];
    int tid = threadIdx.x;
    int per = (Nd + 1023) >> 10;
    int lo = tid * per, hi = lo + per;
    if (lo > Nd) lo = Nd;
    if (hi > Nd) hi = Nd;
    int s = 0;
    for (int i = lo; i < hi; i++) s += deg[i];
    ts[tid] = s;
    __syncthreads();
    for (int off = 1; off < 1024; off <<= 1) {
        int v = (tid >= off) ? ts[tid - off] : 0;
        __syncthreads();
        ts[tid] += v;
        __syncthreads();
    }
    int base = tid ? ts[tid - 1] : 0;
    for (int i = lo; i < hi; i++) { rp[i] = base; base += deg[i]; }
    if (tid == 0) rp[Nd] = E;
}

__global__ void scatter_edges(const int* __restrict__ src, const int* __restrict__ dst,
                              const int* __restrict__ rp, int* __restrict__ cnt,
                              int* __restrict__ ss, int* __restrict__ dd, int E) {
    int t = blockIdx.x * blockDim.x + threadIdx.x;
    if (t >= E) return;
    int d = dst[t];
    int pos = rp[d] + atomicAdd(&cnt[d], 1);
    ss[pos] = src[t];
    dd[pos] = d;
}

// ---------- edge logits on sorted edges ----------
__global__ void edge_e(const int* __restrict__ ss, const int* __restrict__ dd,
                       const float* __restrict__ el, const float* __restrict__ er,
                       float* __restrict__ e, int E) {
    int t = blockIdx.x * blockDim.x + threadIdx.x;
    if (t >= E) return;
    int s = ss[t], d = dd[t];
    float4 l = *(const float4*)(el + (size_t)s * 4);
    float4 r = *(const float4*)(er + (size_t)d * 4);
    float4 v;
    v.x = l.x + r.x; v.x = v.x > 0.f ? v.x : 0.2f * v.x;
    v.y = l.y + r.y; v.y = v.y > 0.f ? v.y : 0.2f * v.y;
    v.z = l.z + r.z; v.z = v.z > 0.f ? v.z : 0.2f * v.z;
    v.w = l.w + r.w; v.w = v.w > 0.f ? v.w : 0.2f * v.w;
    *(float4*)(e + (size_t)t * 4) = v;
}

// ---------- segment softmax in place: e -> alpha; thread per (dst,head) ----------
__global__ void seg_softmax(const int* __restrict__ rp, float* __restrict__ e, int Nd) {
    int t = blockIdx.x * blockDim.x + threadIdx.x;
    if (t >= Nd * 4) return;
    int d = t >> 2, h = t & 3;
    int i0 = rp[d], i1 = rp[d + 1];
    if (i0 == i1) return;
    float m = -FLT_MAX;
    for (int i = i0; i < i1; i++) m = fmaxf(m, e[(size_t)i * 4 + h]);
    float s = 0.f;
    for (int i = i0; i < i1; i++) {
        float v = expf(e[(size_t)i * 4 + h] - m);
        e[(size_t)i * 4 + h] = v;
        s += v;
    }
    float inv = 1.f / s;
    for (int i = i0; i < i1; i++) e[(size_t)i * 4 + h] *= inv;
}

// ---------- aggregate: one wave per dst; bias+relu fused; out fp32 or bf16 ----------
__global__ __launch_bounds__(256) void agg(const int* __restrict__ rp, const int* __restrict__ ss,
                                           const float* __restrict__ alpha,
                                           const __hip_bfloat16* __restrict__ z,
                                           const float* __restrict__ b,
                                           float* __restrict__ outf,
                                           __hip_bfloat16* __restrict__ outb, int Nd) {
    int wave = threadIdx.x >> 6, lane = threadIdx.x & 63;
    int d = blockIdx.x * 4 + wave;
    if (d >= Nd) return;
    int i0 = rp[d], i1 = rp[d + 1];
    float ax = 0.f, ay = 0.f;
    for (int i = i0; i < i1; i++) {
        int s = ss[i];
        float4 a = *(const float4*)(alpha + (size_t)i * 4);
        const unsigned* zr = (const unsigned*)(z + (size_t)s * 512);
        unsigned u0 = zr[lane], u1 = zr[64 + lane], u2 = zr[128 + lane], u3 = zr[192 + lane];
        ax += a.x * blo(u0) + a.y * blo(u1) + a.z * blo(u2) + a.w * blo(u3);
        ay += a.x * bhi(u0) + a.y * bhi(u1) + a.z * bhi(u2) + a.w * bhi(u3);
    }
    int f = lane * 2;
    ax += b[f] + b[128 + f] + b[256 + f] + b[384 + f];
    ay += b[f + 1] + b[129 + f] + b[257 + f] + b[385 + f];
    ax = fmaxf(ax, 0.f);
    ay = fmaxf(ay, 0.f);
    if (outf) {
        *(float2*)(outf + (size_t)d * 128 + f) = make_float2(ax, ay);
    } else {
        __hip_bfloat162 p;
        p.x = __float2bfloat16(ax);
        p.y = __float2bfloat16(ay);
        *(__hip_bfloat162*)(outb + (size_t)d * 128 + f) = p;
    }
}

// ---------- one relation-layer ----------
static void run_rel(const __hip_bfloat16* xsb, int Ns,
                    const void* xdst, bool xdst_is_bf16, int Nd,
                    const int* rp, const int* ss, const int* dd, int E,
                    const float* W, const float* al, const float* ar, const float* b,
                    int K, float* houtf, __hip_bfloat16* houtb, bool same_type,
                    __hip_bfloat16* z, __hip_bfloat16* Wt,
                    float* el, float* er, float* ebuf, float* Wr, hipStream_t stream) {
    transpose_w<<<(512 * K + 255) / 256, 256, 0, stream>>>(W, Wt, K);
    gemm_epi<<<dim3(4, Ns / 128), 256, 0, stream>>>(xsb, Wt, z, al, ar, el,
                                                    same_type ? er : nullptr, Ns, K);
    if (!same_type) {
        make_wr<<<(K * 4 + 255) / 256, 256, 0, stream>>>(W, ar, Wr, K);
        if (xdst_is_bf16)
            attn_bf16<<<(Nd + 3) / 4, 256, 0, stream>>>((const __hip_bfloat16*)xdst, Wr, er, Nd, K);
        else
            attn_f32<<<(Nd + 3) / 4, 256, 0, stream>>>((const float*)xdst, Wr, er, Nd, K);
    }
    edge_e<<<(E + 255) / 256, 256, 0, stream>>>(ss, dd, el, er, ebuf, E);
    seg_softmax<<<(Nd * 4 + 255) / 256, 256, 0, stream>>>(rp, ebuf, Nd);
    agg<<<(Nd + 3) / 4, 256, 0, stream>>>(rp, ss, ebuf, z, b, houtf, houtb, Nd);
}

static inline char* aln(char*& p, size_t bytes) {
    char* r = p;
    p += (bytes + 255) & ~(size_t)255;
    return r;
}

extern "C" void kernel_launch(void* const* d_in, const int* in_sizes, int n_in,
                              void* d_out, int out_size, void* d_ws, size_t ws_size,
                              hipStream_t stream) {
    const float* xw     = (const float*)d_in[0];
    const float* xd     = (const float*)d_in[1];
    const float* W_ww0  = (const float*)d_in[2];
    const float* al_ww0 = (const float*)d_in[3];
    const float* ar_ww0 = (const float*)d_in[4];
    const float* b_ww0  = (const float*)d_in[5];
    const float* W_wd0  = (const float*)d_in[6];
    const float* al_wd0 = (const float*)d_in[7];
    const float* ar_wd0 = (const float*)d_in[8];
    const float* b_wd0  = (const float*)d_in[9];
    const float* W_ww1  = (const float*)d_in[10];
    const float* al_ww1 = (const float*)d_in[11];
    const float* ar_ww1 = (const float*)d_in[12];
    const float* b_ww1  = (const float*)d_in[13];
    const float* W_wd1  = (const float*)d_in[14];
    const float* al_wd1 = (const float*)d_in[15];
    const float* ar_wd1 = (const float*)d_in[16];
    const float* b_wd1  = (const float*)d_in[17];
    const int* ww_src   = (const int*)d_in[18];
    const int* ww_dst   = (const int*)d_in[19];
    const int* wd_src   = (const int*)d_in[20];
    const int* wd_dst   = (const int*)d_in[21];

    // ---- workspace carve ----
    char* p = (char*)d_ws;
    __hip_bfloat16* z    = (__hip_bfloat16*)aln(p, (size_t)NW * 512 * 2);
    __hip_bfloat16* xwb  = (__hip_bfloat16*)aln(p, (size_t)NW * 256 * 2);
    __hip_bfloat16* xw1b = (__hip_bfloat16*)aln(p, (size_t)NW * 128 * 2);
    __hip_bfloat16* xd1b = (__hip_bfloat16*)aln(p, (size_t)ND * 128 * 2);
    __hip_bfloat16* Wt   = (__hip_bfloat16*)aln(p, (size_t)512 * 256 * 2);
    float* el   = (float*)aln(p, (size_t)NW * 4 * 4);
    float* er   = (float*)aln(p, (size_t)NW * 4 * 4);
    float* ebuf = (float*)aln(p, (size_t)EWW * 4 * 4);
    float* Wr   = (float*)aln(p, 4096);
    // CSR ww
    int* rp_ww  = (int*)aln(p, (size_t)(NW + 1) * 4);
    int* deg_ww = (int*)aln(p, (size_t)NW * 2 * 4);   // deg + cnt, one memset
    int* ss_ww  = (int*)aln(p, (size_t)EWW * 4);
    int* dd_ww  = (int*)aln(p, (size_t)EWW * 4);
    // CSR wd
    int* rp_wd  = (int*)aln(p, (size_t)(ND + 1) * 4);
    int* deg_wd = (int*)aln(p, (size_t)ND * 2 * 4);
    int* ss_wd  = (int*)aln(p, (size_t)EWD * 4);
    int* dd_wd  = (int*)aln(p, (size_t)EWD * 4);

    float* out_xw = (float*)d_out;
    float* out_xd = out_xw + (size_t)NW * 128;

    // ---- cast input features ----
    cast_bf16_v4<<<(NW * 256 / 4 + 255) / 256, 256, 0, stream>>>(
        (const float4*)xw, (uint2*)xwb, NW * 256 / 4);

    // ---- CSR build (once per graph, reused by both layers) ----
    hipMemsetAsync(deg_ww, 0, (size_t)NW * 2 * 4, stream);
    hist_k<<<(EWW + 255) / 256, 256, 0, stream>>>(ww_dst, deg_ww, EWW);
    scan_deg<<<1, 1024, 0, stream>>>(deg_ww, rp_ww, NW, EWW);
    scatter_edges<<<(EWW + 255) / 256, 256, 0, stream>>>(ww_src, ww_dst, rp_ww,
                                                         deg_ww + NW, ss_ww, dd_ww, EWW);
    hipMemsetAsync(deg_wd, 0, (size_t)ND * 2 * 4, stream);
    hist_k<<<(EWD + 255) / 256, 256, 0, stream>>>(wd_dst, deg_wd, EWD);
    scan_deg<<<1, 1024, 0, stream>>>(deg_wd, rp_wd, ND, EWD);
    scatter_edges<<<(EWD + 255) / 256, 256, 0, stream>>>(wd_src, wd_dst, rp_wd,
                                                         deg_wd + ND, ss_wd, dd_wd, EWD);

    // ---- layer 0 (K=256): outputs bf16 intermediates ----
    run_rel(xwb, NW, nullptr, false, NW, rp_ww, ss_ww, dd_ww, EWW,
            W_ww0, al_ww0, ar_ww0, b_ww0, 256, nullptr, xw1b, true,
            z, Wt, el, er, ebuf, Wr, stream);
    run_rel(xwb, NW, (const void*)xd, false, ND, rp_wd, ss_wd, dd_wd, EWD,
            W_wd0, al_wd0, ar_wd0, b_wd0, 256, nullptr, xd1b, false,
            z, Wt, el, er, ebuf, Wr, stream);

    // ---- layer 1 (K=128): outputs fp32 straight into d_out (relu fused) ----
    run_rel(xw1b, NW, nullptr, false, NW, rp_ww, ss_ww, dd_ww, EWW,
            W_ww1, al_ww1, ar_ww1, b_ww1, 128, out_xw, nullptr, true,
            z, Wt, el, er, ebuf, Wr, stream);
    run_rel(xw1b, NW, (const void*)xd1b, true, ND, rp_wd, ss_wd, dd_wd, EWD,
            W_wd1, al_wd1, ar_wd1, b_wd1, 128, out_xd, nullptr, false,
            z, Wt, el, er, ebuf, Wr, stream);
}

// Round 4
// 689.620 us; speedup vs baseline: 3.3824x; 1.1851x over previous
//
#include <hip/hip_runtime.h>
#include <hip/hip_bf16.h>
#include <cstddef>
#include <cfloat>

#define NW 80000
#define ND 16000
#define EWW 200000
#define EWD 200000

typedef short v8s __attribute__((ext_vector_type(8)));
typedef float v4f __attribute__((ext_vector_type(4)));

static __device__ __forceinline__ float blo(unsigned u) { return __uint_as_float(u << 16); }
static __device__ __forceinline__ float bhi(unsigned u) { return __uint_as_float(u & 0xffff0000u); }

// ---------- fp32 -> bf16 cast, x4 vectorized ----------
__global__ void cast_bf16_v4(const float4* __restrict__ x, uint2* __restrict__ xb, int n4) {
    int i = blockIdx.x * blockDim.x + threadIdx.x;
    if (i >= n4) return;
    float4 v = x[i];
    __hip_bfloat162 a, b;
    a.x = __float2bfloat16(v.x); a.y = __float2bfloat16(v.y);
    b.x = __float2bfloat16(v.z); b.y = __float2bfloat16(v.w);
    uint2 o;
    o.x = *(unsigned*)&a; o.y = *(unsigned*)&b;
    xb[i] = o;
}

// ---------- W[K,512] -> Wt[512,K] bf16 ----------
__global__ void transpose_w(const float* __restrict__ W, __hip_bfloat16* __restrict__ Wt, int K) {
    int i = blockIdx.x * blockDim.x + threadIdx.x;
    if (i >= 512 * K) return;
    int n = i / K, k = i - n * K;
    Wt[i] = __float2bfloat16(W[k * 512 + n]);
}

// ---------- Wr = per-head contraction of W with ar: [K,4] (dst side of wd) ----------
__global__ void make_wr(const float* __restrict__ W, const float* __restrict__ ar,
                        float* __restrict__ Wr, int K) {
    int i = blockIdx.x * blockDim.x + threadIdx.x;
    if (i >= K * 4) return;
    int k = i >> 2, h = i & 3;
    float sr = 0.f;
    const float* wr = W + (size_t)k * 512 + h * 128;
    const float* arr = ar + h * 128;
    for (int f = 0; f < 128; f++) sr += wr[f] * arr[f];
    Wr[k * 4 + h] = sr;
}

// ---------- er = x @ Wr ([N,4]); one wave per row; fp32 x ----------
__global__ __launch_bounds__(256) void attn_f32(const float* __restrict__ x,
                                                const float* __restrict__ Wv,
                                                float* __restrict__ out, int N, int K) {
    int wave = threadIdx.x >> 6, lane = threadIdx.x & 63;
    int row = blockIdx.x * 4 + wave;
    if (row >= N) return;
    const float* xr = x + (size_t)row * K;
    float a0 = 0.f, a1 = 0.f, a2 = 0.f, a3 = 0.f;
    for (int k = lane; k < K; k += 64) {
        float v = xr[k];
        const float* w = Wv + k * 4;
        a0 += v * w[0]; a1 += v * w[1]; a2 += v * w[2]; a3 += v * w[3];
    }
#pragma unroll
    for (int off = 32; off; off >>= 1) {
        a0 += __shfl_down(a0, off); a1 += __shfl_down(a1, off);
        a2 += __shfl_down(a2, off); a3 += __shfl_down(a3, off);
    }
    if (lane == 0) {
        out[row * 4 + 0] = a0; out[row * 4 + 1] = a1;
        out[row * 4 + 2] = a2; out[row * 4 + 3] = a3;
    }
}

// ---------- bf16-x variant ----------
__global__ __launch_bounds__(256) void attn_bf16(const __hip_bfloat16* __restrict__ x,
                                                 const float* __restrict__ Wv,
                                                 float* __restrict__ out, int N, int K) {
    int wave = threadIdx.x >> 6, lane = threadIdx.x & 63;
    int row = blockIdx.x * 4 + wave;
    if (row >= N) return;
    const __hip_bfloat16* xr = x + (size_t)row * K;
    float a0 = 0.f, a1 = 0.f, a2 = 0.f, a3 = 0.f;
    for (int k = lane; k < K; k += 64) {
        float v = __bfloat162float(xr[k]);
        const float* w = Wv + k * 4;
        a0 += v * w[0]; a1 += v * w[1]; a2 += v * w[2]; a3 += v * w[3];
    }
#pragma unroll
    for (int off = 32; off; off >>= 1) {
        a0 += __shfl_down(a0, off); a1 += __shfl_down(a1, off);
        a2 += __shfl_down(a2, off); a3 += __shfl_down(a3, off);
    }
    if (lane == 0) {
        out[row * 4 + 0] = a0; out[row * 4 + 1] = a1;
        out[row * 4 + 2] = a2; out[row * 4 + 3] = a3;
    }
}

// ---------- bf16 MFMA GEMM + attention-logit epilogue ----------
// C[M,512] = A[M,K] @ B[K,512] (Bt = B^T).  BM=BN=128, BK=32; blockIdx.x = head h.
__global__ __launch_bounds__(256) void gemm_epi(const __hip_bfloat16* __restrict__ A,
                                                const __hip_bfloat16* __restrict__ Bt,
                                                __hip_bfloat16* __restrict__ C,
                                                const float* __restrict__ al,
                                                const float* __restrict__ ar,
                                                float* __restrict__ el,
                                                float* __restrict__ er,
                                                int M, int K) {
    const int N = 512;
    __shared__ short As[128][40];   // pad 32->40: 80B row stride
    __shared__ short Bs[128][40];
    int tid = threadIdx.x;
    int wave = tid >> 6, lane = tid & 63;
    int l16 = lane & 15, quad = lane >> 4;
    int h = blockIdx.x;
    int bm = blockIdx.y * 128, bn = h * 128;
    v4f acc[2][8] = {};
    int r = tid >> 2, ko = (tid & 3) * 8;
    for (int k0 = 0; k0 < K; k0 += 32) {
        *(uint4*)&As[r][ko]      = *(const uint4*)&A[(size_t)(bm + r) * K + k0 + ko];
        *(uint4*)&As[r + 64][ko] = *(const uint4*)&A[(size_t)(bm + r + 64) * K + k0 + ko];
        *(uint4*)&Bs[r][ko]      = *(const uint4*)&Bt[(size_t)(bn + r) * K + k0 + ko];
        *(uint4*)&Bs[r + 64][ko] = *(const uint4*)&Bt[(size_t)(bn + r + 64) * K + k0 + ko];
        __syncthreads();
        v8s a[2], b[8];
#pragma unroll
        for (int rr = 0; rr < 2; rr++) a[rr] = *(v8s*)&As[wave * 32 + rr * 16 + l16][quad * 8];
#pragma unroll
        for (int c = 0; c < 8; c++) b[c] = *(v8s*)&Bs[c * 16 + l16][quad * 8];
#pragma unroll
        for (int rr = 0; rr < 2; rr++)
#pragma unroll
            for (int c = 0; c < 8; c++)
                acc[rr][c] = __builtin_amdgcn_mfma_f32_16x16x32_bf16(a[rr], b[c], acc[rr][c], 0, 0, 0);
        __syncthreads();
    }
    // store z (bf16)
#pragma unroll
    for (int rr = 0; rr < 2; rr++)
#pragma unroll
        for (int c = 0; c < 8; c++)
#pragma unroll
            for (int i = 0; i < 4; i++) {
                int row = bm + wave * 32 + rr * 16 + quad * 4 + i;
                int col = bn + c * 16 + l16;
                C[(size_t)row * N + col] = __float2bfloat16(acc[rr][c][i]);
            }
    // epilogue: el/er via per-lane dot + 16-lane shuffle reduce
    float alv[8], arv[8];
#pragma unroll
    for (int c = 0; c < 8; c++) {
        alv[c] = al[h * 128 + c * 16 + l16];
        arv[c] = ar[h * 128 + c * 16 + l16];
    }
#pragma unroll
    for (int rr = 0; rr < 2; rr++)
#pragma unroll
        for (int i = 0; i < 4; i++) {
            float pl = 0.f, pr = 0.f;
#pragma unroll
            for (int c = 0; c < 8; c++) {
                pl += acc[rr][c][i] * alv[c];
                pr += acc[rr][c][i] * arv[c];
            }
#pragma unroll
            for (int off = 1; off < 16; off <<= 1) {
                pl += __shfl_xor(pl, off);
                pr += __shfl_xor(pr, off);
            }
            if (l16 == 0) {
                int row = bm + wave * 32 + rr * 16 + quad * 4 + i;
                el[(size_t)row * 4 + h] = pl;
                if (er) er[(size_t)row * 4 + h] = pr;
            }
        }
}

// ---------- CSR build ----------
__global__ void hist_k(const int* __restrict__ dst, int* __restrict__ deg, int E) {
    int t = blockIdx.x * blockDim.x + threadIdx.x;
    if (t < E) atomicAdd(&deg[dst[t]], 1);
}

// 3-phase exclusive scan: 1024 elems/block (256 thr x 4)
__global__ __launch_bounds__(256) void scan_block(const int* __restrict__ deg,
                                                  int* __restrict__ rp,
                                                  int* __restrict__ bsum, int N) {
    __shared__ int ts[256];
    int tid = threadIdx.x;
    int base = blockIdx.x * 1024 + tid * 4;
    int v0 = 0, v1 = 0, v2 = 0, v3 = 0;
    if (base + 3 < N) {
        int4 q = *(const int4*)(deg + base);
        v0 = q.x; v1 = q.y; v2 = q.z; v3 = q.w;
    } else {
        if (base + 0 < N) v0 = deg[base + 0];
        if (base + 1 < N) v1 = deg[base + 1];
        if (base + 2 < N) v2 = deg[base + 2];
        if (base + 3 < N) v3 = deg[base + 3];
    }
    int s = v0 + v1 + v2 + v3;
    ts[tid] = s;
    __syncthreads();
    for (int off = 1; off < 256; off <<= 1) {
        int t = (tid >= off) ? ts[tid - off] : 0;
        __syncthreads();
        ts[tid] += t;
        __syncthreads();
    }
    int excl = ts[tid] - s;
    if (tid == 255) bsum[blockIdx.x] = ts[255];
    if (base + 0 < N) rp[base + 0] = excl;
    if (base + 1 < N) rp[base + 1] = excl + v0;
    if (base + 2 < N) rp[base + 2] = excl + v0 + v1;
    if (base + 3 < N) rp[base + 3] = excl + v0 + v1 + v2;
}

__global__ __launch_bounds__(256) void scan_bsum(int* __restrict__ bsum, int nb) {
    __shared__ int ts[256];
    int tid = threadIdx.x;
    int v = (tid < nb) ? bsum[tid] : 0;
    ts[tid] = v;
    __syncthreads();
    for (int off = 1; off < 256; off <<= 1) {
        int t = (tid >= off) ? ts[tid - off] : 0;
        __syncthreads();
        ts[tid] += t;
        __syncthreads();
    }
    if (tid < nb) bsum[tid] = ts[tid] - v;
}

__global__ __launch_bounds__(256) void add_off(int* __restrict__ rp,
                                               const int* __restrict__ bsum,
                                               int N, int E) {
    int tid = threadIdx.x;
    int base = blockIdx.x * 1024 + tid * 4;
    int o = bsum[blockIdx.x];
    if (base + 3 < N) {
        int4 q = *(const int4*)(rp + base);
        q.x += o; q.y += o; q.z += o; q.w += o;
        *(int4*)(rp + base) = q;
    } else {
        if (base + 0 < N) rp[base + 0] += o;
        if (base + 1 < N) rp[base + 1] += o;
        if (base + 2 < N) rp[base + 2] += o;
        if (base + 3 < N) rp[base + 3] += o;
    }
    if (blockIdx.x == 0 && tid == 0) rp[N] = E;
}

__global__ void scatter_edges(const int* __restrict__ src, const int* __restrict__ dst,
                              const int* __restrict__ rp, int* __restrict__ cnt,
                              int* __restrict__ ss, int* __restrict__ dd, int E) {
    int t = blockIdx.x * blockDim.x + threadIdx.x;
    if (t >= E) return;
    int d = dst[t];
    int pos = rp[d] + atomicAdd(&cnt[d], 1);
    ss[pos] = src[t];
    dd[pos] = d;
}

// ---------- edge logits on sorted edges ----------
__global__ void edge_e(const int* __restrict__ ss, const int* __restrict__ dd,
                       const float* __restrict__ el, const float* __restrict__ er,
                       float* __restrict__ e, int E) {
    int t = blockIdx.x * blockDim.x + threadIdx.x;
    if (t >= E) return;
    int s = ss[t], d = dd[t];
    float4 l = *(const float4*)(el + (size_t)s * 4);
    float4 r = *(const float4*)(er + (size_t)d * 4);
    float4 v;
    v.x = l.x + r.x; v.x = v.x > 0.f ? v.x : 0.2f * v.x;
    v.y = l.y + r.y; v.y = v.y > 0.f ? v.y : 0.2f * v.y;
    v.z = l.z + r.z; v.z = v.z > 0.f ? v.z : 0.2f * v.z;
    v.w = l.w + r.w; v.w = v.w > 0.f ? v.w : 0.2f * v.w;
    *(float4*)(e + (size_t)t * 4) = v;
}

// ---------- segment softmax in place: e -> alpha; thread per (dst,head) ----------
__global__ void seg_softmax(const int* __restrict__ rp, float* __restrict__ e, int Nd) {
    int t = blockIdx.x * blockDim.x + threadIdx.x;
    if (t >= Nd * 4) return;
    int d = t >> 2, h = t & 3;
    int i0 = rp[d], i1 = rp[d + 1];
    if (i0 == i1) return;
    float m = -FLT_MAX;
    for (int i = i0; i < i1; i++) m = fmaxf(m, e[(size_t)i * 4 + h]);
    float s = 0.f;
    for (int i = i0; i < i1; i++) {
        float v = expf(e[(size_t)i * 4 + h] - m);
        e[(size_t)i * 4 + h] = v;
        s += v;
    }
    float inv = 1.f / s;
    for (int i = i0; i < i1; i++) e[(size_t)i * 4 + h] *= inv;
}

// ---------- aggregate: one wave per dst; bias+relu fused; out fp32 or bf16 ----------
__global__ __launch_bounds__(256) void agg(const int* __restrict__ rp, const int* __restrict__ ss,
                                           const float* __restrict__ alpha,
                                           const __hip_bfloat16* __restrict__ z,
                                           const float* __restrict__ b,
                                           float* __restrict__ outf,
                                           __hip_bfloat16* __restrict__ outb, int Nd) {
    int wave = threadIdx.x >> 6, lane = threadIdx.x & 63;
    int d = blockIdx.x * 4 + wave;
    if (d >= Nd) return;
    int i0 = rp[d], i1 = rp[d + 1];
    float ax = 0.f, ay = 0.f;
    for (int i = i0; i < i1; i++) {
        int s = ss[i];
        float4 a = *(const float4*)(alpha + (size_t)i * 4);
        const unsigned* zr = (const unsigned*)(z + (size_t)s * 512);
        unsigned u0 = zr[lane], u1 = zr[64 + lane], u2 = zr[128 + lane], u3 = zr[192 + lane];
        ax += a.x * blo(u0) + a.y * blo(u1) + a.z * blo(u2) + a.w * blo(u3);
        ay += a.x * bhi(u0) + a.y * bhi(u1) + a.z * bhi(u2) + a.w * bhi(u3);
    }
    int f = lane * 2;
    ax += b[f] + b[128 + f] + b[256 + f] + b[384 + f];
    ay += b[f + 1] + b[129 + f] + b[257 + f] + b[385 + f];
    ax = fmaxf(ax, 0.f);
    ay = fmaxf(ay, 0.f);
    if (outf) {
        *(float2*)(outf + (size_t)d * 128 + f) = make_float2(ax, ay);
    } else {
        __hip_bfloat162 p;
        p.x = __float2bfloat16(ax);
        p.y = __float2bfloat16(ay);
        *(__hip_bfloat162*)(outb + (size_t)d * 128 + f) = p;
    }
}

// ---------- one relation-layer ----------
static void run_rel(const __hip_bfloat16* xsb, int Ns,
                    const void* xdst, bool xdst_is_bf16, int Nd,
                    const int* rp, const int* ss, const int* dd, int E,
                    const float* W, const float* al, const float* ar, const float* b,
                    int K, float* houtf, __hip_bfloat16* houtb, bool same_type,
                    __hip_bfloat16* z, __hip_bfloat16* Wt,
                    float* el, float* er, float* ebuf, float* Wr, hipStream_t stream) {
    transpose_w<<<(512 * K + 255) / 256, 256, 0, stream>>>(W, Wt, K);
    gemm_epi<<<dim3(4, Ns / 128), 256, 0, stream>>>(xsb, Wt, z, al, ar, el,
                                                    same_type ? er : nullptr, Ns, K);
    if (!same_type) {
        make_wr<<<(K * 4 + 255) / 256, 256, 0, stream>>>(W, ar, Wr, K);
        if (xdst_is_bf16)
            attn_bf16<<<(Nd + 3) / 4, 256, 0, stream>>>((const __hip_bfloat16*)xdst, Wr, er, Nd, K);
        else
            attn_f32<<<(Nd + 3) / 4, 256, 0, stream>>>((const float*)xdst, Wr, er, Nd, K);
    }
    edge_e<<<(E + 255) / 256, 256, 0, stream>>>(ss, dd, el, er, ebuf, E);
    seg_softmax<<<(Nd * 4 + 255) / 256, 256, 0, stream>>>(rp, ebuf, Nd);
    agg<<<(Nd + 3) / 4, 256, 0, stream>>>(rp, ss, ebuf, z, b, houtf, houtb, Nd);
}

static inline char* aln(char*& p, size_t bytes) {
    char* r = p;
    p += (bytes + 255) & ~(size_t)255;
    return r;
}

static void build_csr(const int* src, const int* dst, int Nd, int E,
                      int* rp, int* deg, int* bsum, int* ss, int* dd,
                      hipStream_t stream) {
    hipMemsetAsync(deg, 0, (size_t)Nd * 2 * 4, stream);
    hist_k<<<(E + 255) / 256, 256, 0, stream>>>(dst, deg, E);
    int nb = (Nd + 1023) / 1024;
    scan_block<<<nb, 256, 0, stream>>>(deg, rp, bsum, Nd);
    scan_bsum<<<1, 256, 0, stream>>>(bsum, nb);
    add_off<<<nb, 256, 0, stream>>>(rp, bsum, Nd, E);
    scatter_edges<<<(E + 255) / 256, 256, 0, stream>>>(src, dst, rp, deg + Nd, ss, dd, E);
}

extern "C" void kernel_launch(void* const* d_in, const int* in_sizes, int n_in,
                              void* d_out, int out_size, void* d_ws, size_t ws_size,
                              hipStream_t stream) {
    const float* xw     = (const float*)d_in[0];
    const float* xd     = (const float*)d_in[1];
    const float* W_ww0  = (const float*)d_in[2];
    const float* al_ww0 = (const float*)d_in[3];
    const float* ar_ww0 = (const float*)d_in[4];
    const float* b_ww0  = (const float*)d_in[5];
    const float* W_wd0  = (const float*)d_in[6];
    const float* al_wd0 = (const float*)d_in[7];
    const float* ar_wd0 = (const float*)d_in[8];
    const float* b_wd0  = (const float*)d_in[9];
    const float* W_ww1  = (const float*)d_in[10];
    const float* al_ww1 = (const float*)d_in[11];
    const float* ar_ww1 = (const float*)d_in[12];
    const float* b_ww1  = (const float*)d_in[13];
    const float* W_wd1  = (const float*)d_in[14];
    const float* al_wd1 = (const float*)d_in[15];
    const float* ar_wd1 = (const float*)d_in[16];
    const float* b_wd1  = (const float*)d_in[17];
    const int* ww_src   = (const int*)d_in[18];
    const int* ww_dst   = (const int*)d_in[19];
    const int* wd_src   = (const int*)d_in[20];
    const int* wd_dst   = (const int*)d_in[21];

    // ---- workspace carve ----
    char* p = (char*)d_ws;
    __hip_bfloat16* z    = (__hip_bfloat16*)aln(p, (size_t)NW * 512 * 2);
    __hip_bfloat16* xwb  = (__hip_bfloat16*)aln(p, (size_t)NW * 256 * 2);
    __hip_bfloat16* xw1b = (__hip_bfloat16*)aln(p, (size_t)NW * 128 * 2);
    __hip_bfloat16* xd1b = (__hip_bfloat16*)aln(p, (size_t)ND * 128 * 2);
    __hip_bfloat16* Wt   = (__hip_bfloat16*)aln(p, (size_t)512 * 256 * 2);
    float* el   = (float*)aln(p, (size_t)NW * 4 * 4);
    float* er   = (float*)aln(p, (size_t)NW * 4 * 4);
    float* ebuf = (float*)aln(p, (size_t)EWW * 4 * 4);
    float* Wr   = (float*)aln(p, 4096);
    // CSR ww
    int* rp_ww  = (int*)aln(p, (size_t)(NW + 1) * 4);
    int* deg_ww = (int*)aln(p, (size_t)NW * 2 * 4);   // deg + cnt, one memset
    int* ss_ww  = (int*)aln(p, (size_t)EWW * 4);
    int* dd_ww  = (int*)aln(p, (size_t)EWW * 4);
    // CSR wd
    int* rp_wd  = (int*)aln(p, (size_t)(ND + 1) * 4);
    int* deg_wd = (int*)aln(p, (size_t)ND * 2 * 4);
    int* ss_wd  = (int*)aln(p, (size_t)EWD * 4);
    int* dd_wd  = (int*)aln(p, (size_t)EWD * 4);
    int* bsum   = (int*)aln(p, 1024);   // max 79 block sums

    float* out_xw = (float*)d_out;
    float* out_xd = out_xw + (size_t)NW * 128;

    // ---- cast input features ----
    cast_bf16_v4<<<(NW * 256 / 4 + 255) / 256, 256, 0, stream>>>(
        (const float4*)xw, (uint2*)xwb, NW * 256 / 4);

    // ---- CSR build (once per graph, reused by both layers) ----
    build_csr(ww_src, ww_dst, NW, EWW, rp_ww, deg_ww, bsum, ss_ww, dd_ww, stream);
    build_csr(wd_src, wd_dst, ND, EWD, rp_wd, deg_wd, bsum, ss_wd, dd_wd, stream);

    // ---- layer 0 (K=256): outputs bf16 intermediates ----
    run_rel(xwb, NW, nullptr, false, NW, rp_ww, ss_ww, dd_ww, EWW,
            W_ww0, al_ww0, ar_ww0, b_ww0, 256, nullptr, xw1b, true,
            z, Wt, el, er, ebuf, Wr, stream);
    run_rel(xwb, NW, (const void*)xd, false, ND, rp_wd, ss_wd, dd_wd, EWD,
            W_wd0, al_wd0, ar_wd0, b_wd0, 256, nullptr, xd1b, false,
            z, Wt, el, er, ebuf, Wr, stream);

    // ---- layer 1 (K=128): outputs fp32 straight into d_out (relu fused) ----
    run_rel(xw1b, NW, nullptr, false, NW, rp_ww, ss_ww, dd_ww, EWW,
            W_ww1, al_ww1, ar_ww1, b_ww1, 128, out_xw, nullptr, true,
            z, Wt, el, er, ebuf, Wr, stream);
    run_rel(xw1b, NW, (const void*)xd1b, true, ND, rp_wd, ss_wd, dd_wd, EWD,
            W_wd1, al_wd1, ar_wd1, b_wd1, 128, out_xd, nullptr, false,
            z, Wt, el, er, ebuf, Wr, stream);
}

// Round 5
// 670.926 us; speedup vs baseline: 3.4766x; 1.0279x over previous
//
#include <hip/hip_runtime.h>
#include <hip/hip_bf16.h>
#include <cstddef>
#include <cfloat>

#define NW 80000
#define ND 16000
#define EWW 200000
#define EWD 200000

typedef short v8s __attribute__((ext_vector_type(8)));
typedef float v4f __attribute__((ext_vector_type(4)));

static __device__ __forceinline__ float blo(unsigned u) { return __uint_as_float(u << 16); }
static __device__ __forceinline__ float bhi(unsigned u) { return __uint_as_float(u & 0xffff0000u); }

// async global->LDS 16B copy: lane i of the wave writes lds_base + i*16
static __device__ __forceinline__ void gl2lds16(const void* g, void* l) {
    __builtin_amdgcn_global_load_lds((__attribute__((address_space(1))) void*)g,
                                     (__attribute__((address_space(3))) void*)l, 16, 0, 0);
}

// ---------- fp32 -> bf16 cast, x4 vectorized ----------
__global__ void cast_bf16_v4(const float4* __restrict__ x, uint2* __restrict__ xb, int n4) {
    int i = blockIdx.x * blockDim.x + threadIdx.x;
    if (i >= n4) return;
    float4 v = x[i];
    __hip_bfloat162 a, b;
    a.x = __float2bfloat16(v.x); a.y = __float2bfloat16(v.y);
    b.x = __float2bfloat16(v.z); b.y = __float2bfloat16(v.w);
    uint2 o;
    o.x = *(unsigned*)&a; o.y = *(unsigned*)&b;
    xb[i] = o;
}

// ---------- W[K,512] -> Wt[512,K] bf16 ----------
__global__ void transpose_w(const float* __restrict__ W, __hip_bfloat16* __restrict__ Wt, int K) {
    int i = blockIdx.x * blockDim.x + threadIdx.x;
    if (i >= 512 * K) return;
    int n = i / K, k = i - n * K;
    Wt[i] = __float2bfloat16(W[k * 512 + n]);
}

// ---------- Wr = per-head contraction of W with ar: [K,4] (dst side of wd) ----------
__global__ void make_wr(const float* __restrict__ W, const float* __restrict__ ar,
                        float* __restrict__ Wr, int K) {
    int i = blockIdx.x * blockDim.x + threadIdx.x;
    if (i >= K * 4) return;
    int k = i >> 2, h = i & 3;
    float sr = 0.f;
    const float* wr = W + (size_t)k * 512 + h * 128;
    const float* arr = ar + h * 128;
    for (int f = 0; f < 128; f++) sr += wr[f] * arr[f];
    Wr[k * 4 + h] = sr;
}

// ---------- er = x @ Wr ([N,4]); one wave per row; fp32 x ----------
__global__ __launch_bounds__(256) void attn_f32(const float* __restrict__ x,
                                                const float* __restrict__ Wv,
                                                float* __restrict__ out, int N, int K) {
    int wave = threadIdx.x >> 6, lane = threadIdx.x & 63;
    int row = blockIdx.x * 4 + wave;
    if (row >= N) return;
    const float* xr = x + (size_t)row * K;
    float a0 = 0.f, a1 = 0.f, a2 = 0.f, a3 = 0.f;
    for (int k = lane; k < K; k += 64) {
        float v = xr[k];
        const float* w = Wv + k * 4;
        a0 += v * w[0]; a1 += v * w[1]; a2 += v * w[2]; a3 += v * w[3];
    }
#pragma unroll
    for (int off = 32; off; off >>= 1) {
        a0 += __shfl_down(a0, off); a1 += __shfl_down(a1, off);
        a2 += __shfl_down(a2, off); a3 += __shfl_down(a3, off);
    }
    if (lane == 0) {
        out[row * 4 + 0] = a0; out[row * 4 + 1] = a1;
        out[row * 4 + 2] = a2; out[row * 4 + 3] = a3;
    }
}

// ---------- bf16-x variant ----------
__global__ __launch_bounds__(256) void attn_bf16(const __hip_bfloat16* __restrict__ x,
                                                 const float* __restrict__ Wv,
                                                 float* __restrict__ out, int N, int K) {
    int wave = threadIdx.x >> 6, lane = threadIdx.x & 63;
    int row = blockIdx.x * 4 + wave;
    if (row >= N) return;
    const __hip_bfloat16* xr = x + (size_t)row * K;
    float a0 = 0.f, a1 = 0.f, a2 = 0.f, a3 = 0.f;
    for (int k = lane; k < K; k += 64) {
        float v = __bfloat162float(xr[k]);
        const float* w = Wv + k * 4;
        a0 += v * w[0]; a1 += v * w[1]; a2 += v * w[2]; a3 += v * w[3];
    }
#pragma unroll
    for (int off = 32; off; off >>= 1) {
        a0 += __shfl_down(a0, off); a1 += __shfl_down(a1, off);
        a2 += __shfl_down(a2, off); a3 += __shfl_down(a3, off);
    }
    if (lane == 0) {
        out[row * 4 + 0] = a0; out[row * 4 + 1] = a1;
        out[row * 4 + 2] = a2; out[row * 4 + 3] = a3;
    }
}

// ---------- bf16 MFMA GEMM + attention-logit epilogue ----------
// C[M,512] = A[M,K] @ B[K,512] (Bt = B^T [512,K]).  BM=BN=128, BK=64.
// blockIdx.x = head h.  Staging: global_load_lds 16B, XOR-swizzled LDS
// (chunk c of row r at slot c^(r&7); row stride 128B unpadded).  ds_read_b128
// then hits each 4-bank group exactly 2x per 16 lanes (2-way alias = free).
__global__ __launch_bounds__(256) void gemm_epi(const __hip_bfloat16* __restrict__ A,
                                                const __hip_bfloat16* __restrict__ Bt,
                                                __hip_bfloat16* __restrict__ C,
                                                const float* __restrict__ al,
                                                const float* __restrict__ ar,
                                                float* __restrict__ el,
                                                float* __restrict__ er,
                                                int M, int K) {
    const int N = 512;
    __shared__ short AsF[128 * 64];   // 16 KB, row stride 64 shorts
    __shared__ short BsF[128 * 64];
    int tid = threadIdx.x;
    int wave = tid >> 6, lane = tid & 63;
    int l16 = lane & 15, quad = lane >> 4;
    int h = blockIdx.x;
    int bm = blockIdx.y * 128, bn = h * 128;
    v4f acc[2][8] = {};

    // staging source: lane i covers row (base + i>>3), swizzled chunk (i&7)^(i>>3)
    int laneR = lane >> 3;                 // 0..7
    int laneC = (lane & 7) ^ laneR;        // swizzled 16B-chunk index
    const __hip_bfloat16* ga = A  + (size_t)(bm + wave * 32 + laneR) * K + laneC * 8;
    const __hip_bfloat16* gb = Bt + (size_t)(bn + wave * 32 + laneR) * K + laneC * 8;
    short* la = &AsF[(wave * 32) * 64];
    short* lb = &BsF[(wave * 32) * 64];

    for (int k0 = 0; k0 < K; k0 += 64) {
#pragma unroll
        for (int j = 0; j < 4; j++) {
            gl2lds16(ga + (size_t)(j * 8) * K + k0, la + j * 512);
            gl2lds16(gb + (size_t)(j * 8) * K + k0, lb + j * 512);
        }
        __syncthreads();   // drains vmcnt (global_load_lds) before ds_read
#pragma unroll
        for (int kh = 0; kh < 2; kh++) {
            int s = (kh * 4 + quad) ^ (l16 & 7);   // swizzled slot for this lane
            v8s a[2], b[8];
#pragma unroll
            for (int rr = 0; rr < 2; rr++) {
                int r = wave * 32 + rr * 16 + l16;
                a[rr] = *(v8s*)&AsF[r * 64 + s * 8];
            }
#pragma unroll
            for (int c = 0; c < 8; c++) {
                int n = c * 16 + l16;
                b[c] = *(v8s*)&BsF[n * 64 + s * 8];
            }
#pragma unroll
            for (int rr = 0; rr < 2; rr++)
#pragma unroll
                for (int c = 0; c < 8; c++)
                    acc[rr][c] = __builtin_amdgcn_mfma_f32_16x16x32_bf16(a[rr], b[c], acc[rr][c], 0, 0, 0);
        }
        __syncthreads();
    }
    // store z (bf16)
#pragma unroll
    for (int rr = 0; rr < 2; rr++)
#pragma unroll
        for (int c = 0; c < 8; c++)
#pragma unroll
            for (int i = 0; i < 4; i++) {
                int row = bm + wave * 32 + rr * 16 + quad * 4 + i;
                int col = bn + c * 16 + l16;
                C[(size_t)row * N + col] = __float2bfloat16(acc[rr][c][i]);
            }
    // epilogue: el/er via per-lane dot + 16-lane shuffle reduce
    float alv[8], arv[8];
#pragma unroll
    for (int c = 0; c < 8; c++) {
        alv[c] = al[h * 128 + c * 16 + l16];
        arv[c] = ar[h * 128 + c * 16 + l16];
    }
#pragma unroll
    for (int rr = 0; rr < 2; rr++)
#pragma unroll
        for (int i = 0; i < 4; i++) {
            float pl = 0.f, pr = 0.f;
#pragma unroll
            for (int c = 0; c < 8; c++) {
                pl += acc[rr][c][i] * alv[c];
                pr += acc[rr][c][i] * arv[c];
            }
#pragma unroll
            for (int off = 1; off < 16; off <<= 1) {
                pl += __shfl_xor(pl, off);
                pr += __shfl_xor(pr, off);
            }
            if (l16 == 0) {
                int row = bm + wave * 32 + rr * 16 + quad * 4 + i;
                el[(size_t)row * 4 + h] = pl;
                if (er) er[(size_t)row * 4 + h] = pr;
            }
        }
}

// ---------- CSR build ----------
__global__ void hist_k(const int* __restrict__ dst, int* __restrict__ deg, int E) {
    int t = blockIdx.x * blockDim.x + threadIdx.x;
    if (t < E) atomicAdd(&deg[dst[t]], 1);
}

// 3-phase exclusive scan: 1024 elems/block (256 thr x 4)
__global__ __launch_bounds__(256) void scan_block(const int* __restrict__ deg,
                                                  int* __restrict__ rp,
                                                  int* __restrict__ bsum, int N) {
    __shared__ int ts[256];
    int tid = threadIdx.x;
    int base = blockIdx.x * 1024 + tid * 4;
    int v0 = 0, v1 = 0, v2 = 0, v3 = 0;
    if (base + 3 < N) {
        int4 q = *(const int4*)(deg + base);
        v0 = q.x; v1 = q.y; v2 = q.z; v3 = q.w;
    } else {
        if (base + 0 < N) v0 = deg[base + 0];
        if (base + 1 < N) v1 = deg[base + 1];
        if (base + 2 < N) v2 = deg[base + 2];
        if (base + 3 < N) v3 = deg[base + 3];
    }
    int s = v0 + v1 + v2 + v3;
    ts[tid] = s;
    __syncthreads();
    for (int off = 1; off < 256; off <<= 1) {
        int t = (tid >= off) ? ts[tid - off] : 0;
        __syncthreads();
        ts[tid] += t;
        __syncthreads();
    }
    int excl = ts[tid] - s;
    if (tid == 255) bsum[blockIdx.x] = ts[255];
    if (base + 0 < N) rp[base + 0] = excl;
    if (base + 1 < N) rp[base + 1] = excl + v0;
    if (base + 2 < N) rp[base + 2] = excl + v0 + v1;
    if (base + 3 < N) rp[base + 3] = excl + v0 + v1 + v2;
}

__global__ __launch_bounds__(256) void scan_bsum(int* __restrict__ bsum, int nb) {
    __shared__ int ts[256];
    int tid = threadIdx.x;
    int v = (tid < nb) ? bsum[tid] : 0;
    ts[tid] = v;
    __syncthreads();
    for (int off = 1; off < 256; off <<= 1) {
        int t = (tid >= off) ? ts[tid - off] : 0;
        __syncthreads();
        ts[tid] += t;
        __syncthreads();
    }
    if (tid < nb) bsum[tid] = ts[tid] - v;
}

__global__ __launch_bounds__(256) void add_off(int* __restrict__ rp,
                                               const int* __restrict__ bsum,
                                               int N, int E) {
    int tid = threadIdx.x;
    int base = blockIdx.x * 1024 + tid * 4;
    int o = bsum[blockIdx.x];
    if (base + 3 < N) {
        int4 q = *(const int4*)(rp + base);
        q.x += o; q.y += o; q.z += o; q.w += o;
        *(int4*)(rp + base) = q;
    } else {
        if (base + 0 < N) rp[base + 0] += o;
        if (base + 1 < N) rp[base + 1] += o;
        if (base + 2 < N) rp[base + 2] += o;
        if (base + 3 < N) rp[base + 3] += o;
    }
    if (blockIdx.x == 0 && tid == 0) rp[N] = E;
}

__global__ void scatter_edges(const int* __restrict__ src, const int* __restrict__ dst,
                              const int* __restrict__ rp, int* __restrict__ cnt,
                              int* __restrict__ ss, int* __restrict__ dd, int E) {
    int t = blockIdx.x * blockDim.x + threadIdx.x;
    if (t >= E) return;
    int d = dst[t];
    int pos = rp[d] + atomicAdd(&cnt[d], 1);
    ss[pos] = src[t];
    dd[pos] = d;
}

// ---------- edge logits on sorted edges ----------
__global__ void edge_e(const int* __restrict__ ss, const int* __restrict__ dd,
                       const float* __restrict__ el, const float* __restrict__ er,
                       float* __restrict__ e, int E) {
    int t = blockIdx.x * blockDim.x + threadIdx.x;
    if (t >= E) return;
    int s = ss[t], d = dd[t];
    float4 l = *(const float4*)(el + (size_t)s * 4);
    float4 r = *(const float4*)(er + (size_t)d * 4);
    float4 v;
    v.x = l.x + r.x; v.x = v.x > 0.f ? v.x : 0.2f * v.x;
    v.y = l.y + r.y; v.y = v.y > 0.f ? v.y : 0.2f * v.y;
    v.z = l.z + r.z; v.z = v.z > 0.f ? v.z : 0.2f * v.z;
    v.w = l.w + r.w; v.w = v.w > 0.f ? v.w : 0.2f * v.w;
    *(float4*)(e + (size_t)t * 4) = v;
}

// ---------- segment softmax in place: e -> alpha; thread per (dst,head) ----------
__global__ void seg_softmax(const int* __restrict__ rp, float* __restrict__ e, int Nd) {
    int t = blockIdx.x * blockDim.x + threadIdx.x;
    if (t >= Nd * 4) return;
    int d = t >> 2, h = t & 3;
    int i0 = rp[d], i1 = rp[d + 1];
    if (i0 == i1) return;
    float m = -FLT_MAX;
    for (int i = i0; i < i1; i++) m = fmaxf(m, e[(size_t)i * 4 + h]);
    float s = 0.f;
    for (int i = i0; i < i1; i++) {
        float v = expf(e[(size_t)i * 4 + h] - m);
        e[(size_t)i * 4 + h] = v;
        s += v;
    }
    float inv = 1.f / s;
    for (int i = i0; i < i1; i++) e[(size_t)i * 4 + h] *= inv;
}

// ---------- aggregate: one wave per dst; bias+relu fused; out fp32 or bf16 ----------
__global__ __launch_bounds__(256) void agg(const int* __restrict__ rp, const int* __restrict__ ss,
                                           const float* __restrict__ alpha,
                                           const __hip_bfloat16* __restrict__ z,
                                           const float* __restrict__ b,
                                           float* __restrict__ outf,
                                           __hip_bfloat16* __restrict__ outb, int Nd) {
    int wave = threadIdx.x >> 6, lane = threadIdx.x & 63;
    int d = blockIdx.x * 4 + wave;
    if (d >= Nd) return;
    int i0 = rp[d], i1 = rp[d + 1];
    float ax = 0.f, ay = 0.f;
    for (int i = i0; i < i1; i++) {
        int s = ss[i];
        float4 a = *(const float4*)(alpha + (size_t)i * 4);
        const unsigned* zr = (const unsigned*)(z + (size_t)s * 512);
        unsigned u0 = zr[lane], u1 = zr[64 + lane], u2 = zr[128 + lane], u3 = zr[192 + lane];
        ax += a.x * blo(u0) + a.y * blo(u1) + a.z * blo(u2) + a.w * blo(u3);
        ay += a.x * bhi(u0) + a.y * bhi(u1) + a.z * bhi(u2) + a.w * bhi(u3);
    }
    int f = lane * 2;
    ax += b[f] + b[128 + f] + b[256 + f] + b[384 + f];
    ay += b[f + 1] + b[129 + f] + b[257 + f] + b[385 + f];
    ax = fmaxf(ax, 0.f);
    ay = fmaxf(ay, 0.f);
    if (outf) {
        *(float2*)(outf + (size_t)d * 128 + f) = make_float2(ax, ay);
    } else {
        __hip_bfloat162 p;
        p.x = __float2bfloat16(ax);
        p.y = __float2bfloat16(ay);
        *(__hip_bfloat162*)(outb + (size_t)d * 128 + f) = p;
    }
}

// ---------- one relation-layer ----------
static void run_rel(const __hip_bfloat16* xsb, int Ns,
                    const void* xdst, bool xdst_is_bf16, int Nd,
                    const int* rp, const int* ss, const int* dd, int E,
                    const float* W, const float* al, const float* ar, const float* b,
                    int K, float* houtf, __hip_bfloat16* houtb, bool same_type,
                    __hip_bfloat16* z, __hip_bfloat16* Wt,
                    float* el, float* er, float* ebuf, float* Wr, hipStream_t stream) {
    transpose_w<<<(512 * K + 255) / 256, 256, 0, stream>>>(W, Wt, K);
    gemm_epi<<<dim3(4, Ns / 128), 256, 0, stream>>>(xsb, Wt, z, al, ar, el,
                                                    same_type ? er : nullptr, Ns, K);
    if (!same_type) {
        make_wr<<<(K * 4 + 255) / 256, 256, 0, stream>>>(W, ar, Wr, K);
        if (xdst_is_bf16)
            attn_bf16<<<(Nd + 3) / 4, 256, 0, stream>>>((const __hip_bfloat16*)xdst, Wr, er, Nd, K);
        else
            attn_f32<<<(Nd + 3) / 4, 256, 0, stream>>>((const float*)xdst, Wr, er, Nd, K);
    }
    edge_e<<<(E + 255) / 256, 256, 0, stream>>>(ss, dd, el, er, ebuf, E);
    seg_softmax<<<(Nd * 4 + 255) / 256, 256, 0, stream>>>(rp, ebuf, Nd);
    agg<<<(Nd + 3) / 4, 256, 0, stream>>>(rp, ss, ebuf, z, b, houtf, houtb, Nd);
}

static inline char* aln(char*& p, size_t bytes) {
    char* r = p;
    p += (bytes + 255) & ~(size_t)255;
    return r;
}

static void build_csr(const int* src, const int* dst, int Nd, int E,
                      int* rp, int* deg, int* bsum, int* ss, int* dd,
                      hipStream_t stream) {
    hipMemsetAsync(deg, 0, (size_t)Nd * 2 * 4, stream);
    hist_k<<<(E + 255) / 256, 256, 0, stream>>>(dst, deg, E);
    int nb = (Nd + 1023) / 1024;
    scan_block<<<nb, 256, 0, stream>>>(deg, rp, bsum, Nd);
    scan_bsum<<<1, 256, 0, stream>>>(bsum, nb);
    add_off<<<nb, 256, 0, stream>>>(rp, bsum, Nd, E);
    scatter_edges<<<(E + 255) / 256, 256, 0, stream>>>(src, dst, rp, deg + Nd, ss, dd, E);
}

extern "C" void kernel_launch(void* const* d_in, const int* in_sizes, int n_in,
                              void* d_out, int out_size, void* d_ws, size_t ws_size,
                              hipStream_t stream) {
    const float* xw     = (const float*)d_in[0];
    const float* xd     = (const float*)d_in[1];
    const float* W_ww0  = (const float*)d_in[2];
    const float* al_ww0 = (const float*)d_in[3];
    const float* ar_ww0 = (const float*)d_in[4];
    const float* b_ww0  = (const float*)d_in[5];
    const float* W_wd0  = (const float*)d_in[6];
    const float* al_wd0 = (const float*)d_in[7];
    const float* ar_wd0 = (const float*)d_in[8];
    const float* b_wd0  = (const float*)d_in[9];
    const float* W_ww1  = (const float*)d_in[10];
    const float* al_ww1 = (const float*)d_in[11];
    const float* ar_ww1 = (const float*)d_in[12];
    const float* b_ww1  = (const float*)d_in[13];
    const float* W_wd1  = (const float*)d_in[14];
    const float* al_wd1 = (const float*)d_in[15];
    const float* ar_wd1 = (const float*)d_in[16];
    const float* b_wd1  = (const float*)d_in[17];
    const int* ww_src   = (const int*)d_in[18];
    const int* ww_dst   = (const int*)d_in[19];
    const int* wd_src   = (const int*)d_in[20];
    const int* wd_dst   = (const int*)d_in[21];

    // ---- workspace carve ----
    char* p = (char*)d_ws;
    __hip_bfloat16* z    = (__hip_bfloat16*)aln(p, (size_t)NW * 512 * 2);
    __hip_bfloat16* xwb  = (__hip_bfloat16*)aln(p, (size_t)NW * 256 * 2);
    __hip_bfloat16* xw1b = (__hip_bfloat16*)aln(p, (size_t)NW * 128 * 2);
    __hip_bfloat16* xd1b = (__hip_bfloat16*)aln(p, (size_t)ND * 128 * 2);
    __hip_bfloat16* Wt   = (__hip_bfloat16*)aln(p, (size_t)512 * 256 * 2);
    float* el   = (float*)aln(p, (size_t)NW * 4 * 4);
    float* er   = (float*)aln(p, (size_t)NW * 4 * 4);
    float* ebuf = (float*)aln(p, (size_t)EWW * 4 * 4);
    float* Wr   = (float*)aln(p, 4096);
    // CSR ww
    int* rp_ww  = (int*)aln(p, (size_t)(NW + 1) * 4);
    int* deg_ww = (int*)aln(p, (size_t)NW * 2 * 4);   // deg + cnt, one memset
    int* ss_ww  = (int*)aln(p, (size_t)EWW * 4);
    int* dd_ww  = (int*)aln(p, (size_t)EWW * 4);
    // CSR wd
    int* rp_wd  = (int*)aln(p, (size_t)(ND + 1) * 4);
    int* deg_wd = (int*)aln(p, (size_t)ND * 2 * 4);
    int* ss_wd  = (int*)aln(p, (size_t)EWD * 4);
    int* dd_wd  = (int*)aln(p, (size_t)EWD * 4);
    int* bsum   = (int*)aln(p, 1024);   // max 79 block sums

    float* out_xw = (float*)d_out;
    float* out_xd = out_xw + (size_t)NW * 128;

    // ---- cast input features ----
    cast_bf16_v4<<<(NW * 256 / 4 + 255) / 256, 256, 0, stream>>>(
        (const float4*)xw, (uint2*)xwb, NW * 256 / 4);

    // ---- CSR build (once per graph, reused by both layers) ----
    build_csr(ww_src, ww_dst, NW, EWW, rp_ww, deg_ww, bsum, ss_ww, dd_ww, stream);
    build_csr(wd_src, wd_dst, ND, EWD, rp_wd, deg_wd, bsum, ss_wd, dd_wd, stream);

    // ---- layer 0 (K=256): outputs bf16 intermediates ----
    run_rel(xwb, NW, nullptr, false, NW, rp_ww, ss_ww, dd_ww, EWW,
            W_ww0, al_ww0, ar_ww0, b_ww0, 256, nullptr, xw1b, true,
            z, Wt, el, er, ebuf, Wr, stream);
    run_rel(xwb, NW, (const void*)xd, false, ND, rp_wd, ss_wd, dd_wd, EWD,
            W_wd0, al_wd0, ar_wd0, b_wd0, 256, nullptr, xd1b, false,
            z, Wt, el, er, ebuf, Wr, stream);

    // ---- layer 1 (K=128): outputs fp32 straight into d_out (relu fused) ----
    run_rel(xw1b, NW, nullptr, false, NW, rp_ww, ss_ww, dd_ww, EWW,
            W_ww1, al_ww1, ar_ww1, b_ww1, 128, out_xw, nullptr, true,
            z, Wt, el, er, ebuf, Wr, stream);
    run_rel(xw1b, NW, (const void*)xd1b, true, ND, rp_wd, ss_wd, dd_wd, EWD,
            W_wd1, al_wd1, ar_wd1, b_wd1, 128, out_xd, nullptr, false,
            z, Wt, el, er, ebuf, Wr, stream);
}

// Round 6
// 640.448 us; speedup vs baseline: 3.6421x; 1.0476x over previous
//
#include <hip/hip_runtime.h>
#include <hip/hip_bf16.h>
#include <cstddef>
#include <cfloat>

#define NW 80000
#define ND 16000
#define EWW 200000
#define EWD 200000

typedef short v8s __attribute__((ext_vector_type(8)));
typedef float v4f __attribute__((ext_vector_type(4)));

static __device__ __forceinline__ float blo(unsigned u) { return __uint_as_float(u << 16); }
static __device__ __forceinline__ float bhi(unsigned u) { return __uint_as_float(u & 0xffff0000u); }

// async global->LDS 16B copy: lane i of the wave writes lds_base + i*16
static __device__ __forceinline__ void gl2lds16(const void* g, void* l) {
    __builtin_amdgcn_global_load_lds((__attribute__((address_space(1))) void*)g,
                                     (__attribute__((address_space(3))) void*)l, 16, 0, 0);
}

// ---------- fp32 -> bf16 cast, x4 vectorized ----------
__global__ void cast_bf16_v4(const float4* __restrict__ x, uint2* __restrict__ xb, int n4) {
    int i = blockIdx.x * blockDim.x + threadIdx.x;
    if (i >= n4) return;
    float4 v = x[i];
    __hip_bfloat162 a, b;
    a.x = __float2bfloat16(v.x); a.y = __float2bfloat16(v.y);
    b.x = __float2bfloat16(v.z); b.y = __float2bfloat16(v.w);
    uint2 o;
    o.x = *(unsigned*)&a; o.y = *(unsigned*)&b;
    xb[i] = o;
}

// ---------- [Wa | Wb] ([K,512] each) -> Wt[1024,K] bf16 ----------
__global__ void transpose_w2(const float* __restrict__ Wa, const float* __restrict__ Wb,
                             __hip_bfloat16* __restrict__ Wt, int K) {
    int i = blockIdx.x * blockDim.x + threadIdx.x;
    if (i >= 1024 * K) return;
    int n = i / K, k = i - n * K;
    float v = (n < 512) ? Wa[k * 512 + n] : Wb[k * 512 + (n - 512)];
    Wt[i] = __float2bfloat16(v);
}

// ---------- Wr = per-head contraction of W with ar: [K,4] (dst side of wd) ----------
__global__ void make_wr(const float* __restrict__ W, const float* __restrict__ ar,
                        float* __restrict__ Wr, int K) {
    int i = blockIdx.x * blockDim.x + threadIdx.x;
    if (i >= K * 4) return;
    int k = i >> 2, h = i & 3;
    float sr = 0.f;
    const float* wr = W + (size_t)k * 512 + h * 128;
    const float* arr = ar + h * 128;
    for (int f = 0; f < 128; f++) sr += wr[f] * arr[f];
    Wr[k * 4 + h] = sr;
}

// ---------- er = x @ Wr ([N,4]); one wave per row; fp32 x ----------
__global__ __launch_bounds__(256) void attn_f32(const float* __restrict__ x,
                                                const float* __restrict__ Wv,
                                                float* __restrict__ out, int N, int K) {
    int wave = threadIdx.x >> 6, lane = threadIdx.x & 63;
    int row = blockIdx.x * 4 + wave;
    if (row >= N) return;
    const float* xr = x + (size_t)row * K;
    float a0 = 0.f, a1 = 0.f, a2 = 0.f, a3 = 0.f;
    for (int k = lane; k < K; k += 64) {
        float v = xr[k];
        const float* w = Wv + k * 4;
        a0 += v * w[0]; a1 += v * w[1]; a2 += v * w[2]; a3 += v * w[3];
    }
#pragma unroll
    for (int off = 32; off; off >>= 1) {
        a0 += __shfl_down(a0, off); a1 += __shfl_down(a1, off);
        a2 += __shfl_down(a2, off); a3 += __shfl_down(a3, off);
    }
    if (lane == 0) {
        out[row * 4 + 0] = a0; out[row * 4 + 1] = a1;
        out[row * 4 + 2] = a2; out[row * 4 + 3] = a3;
    }
}

// ---------- bf16-x variant ----------
__global__ __launch_bounds__(256) void attn_bf16(const __hip_bfloat16* __restrict__ x,
                                                 const float* __restrict__ Wv,
                                                 float* __restrict__ out, int N, int K) {
    int wave = threadIdx.x >> 6, lane = threadIdx.x & 63;
    int row = blockIdx.x * 4 + wave;
    if (row >= N) return;
    const __hip_bfloat16* xr = x + (size_t)row * K;
    float a0 = 0.f, a1 = 0.f, a2 = 0.f, a3 = 0.f;
    for (int k = lane; k < K; k += 64) {
        float v = __bfloat162float(xr[k]);
        const float* w = Wv + k * 4;
        a0 += v * w[0]; a1 += v * w[1]; a2 += v * w[2]; a3 += v * w[3];
    }
#pragma unroll
    for (int off = 32; off; off >>= 1) {
        a0 += __shfl_down(a0, off); a1 += __shfl_down(a1, off);
        a2 += __shfl_down(a2, off); a3 += __shfl_down(a3, off);
    }
    if (lane == 0) {
        out[row * 4 + 0] = a0; out[row * 4 + 1] = a1;
        out[row * 4 + 2] = a2; out[row * 4 + 3] = a3;
    }
}

// ---------- merged bf16 MFMA GEMM (both relations) + attention-logit epilogue ----------
// z[M,1024] = A[M,K] @ [W_ww | W_wd]  (Bt = concat^T [1024,K]).  BM=128, BK=64.
// blockIdx.x = h in 0..7: h<4 -> ww head h; h>=4 -> wd head h-4.
// Staging: global_load_lds 16B, XOR-swizzled LDS (chunk c of row r at c^(r&7)).
// Epilogue: ww heads write el0/er0; wd heads write el1 (er of wd comes from x_dst).
__global__ __launch_bounds__(256) void gemm_epi(const __hip_bfloat16* __restrict__ A,
                                                const __hip_bfloat16* __restrict__ Bt,
                                                __hip_bfloat16* __restrict__ C,
                                                const float* __restrict__ al0,
                                                const float* __restrict__ ar0,
                                                const float* __restrict__ al1,
                                                float* __restrict__ el0,
                                                float* __restrict__ er0,
                                                float* __restrict__ el1,
                                                int M, int K) {
    const int N = 1024;
    __shared__ short AsF[128 * 64];   // 16 KB, row stride 64 shorts
    __shared__ short BsF[128 * 64];
    int tid = threadIdx.x;
    int wave = tid >> 6, lane = tid & 63;
    int l16 = lane & 15, quad = lane >> 4;
    int h = blockIdx.x;
    bool isww = h < 4;
    int hh = isww ? h : h - 4;
    int bm = blockIdx.y * 128, bn = h * 128;
    v4f acc[2][8] = {};

    int laneR = lane >> 3;                 // 0..7
    int laneC = (lane & 7) ^ laneR;        // swizzled 16B-chunk index
    const __hip_bfloat16* ga = A  + (size_t)(bm + wave * 32 + laneR) * K + laneC * 8;
    const __hip_bfloat16* gb = Bt + (size_t)(bn + wave * 32 + laneR) * K + laneC * 8;
    short* la = &AsF[(wave * 32) * 64];
    short* lb = &BsF[(wave * 32) * 64];

    for (int k0 = 0; k0 < K; k0 += 64) {
#pragma unroll
        for (int j = 0; j < 4; j++) {
            gl2lds16(ga + (size_t)(j * 8) * K + k0, la + j * 512);
            gl2lds16(gb + (size_t)(j * 8) * K + k0, lb + j * 512);
        }
        __syncthreads();
#pragma unroll
        for (int kh = 0; kh < 2; kh++) {
            int s = (kh * 4 + quad) ^ (l16 & 7);
            v8s a[2], b[8];
#pragma unroll
            for (int rr = 0; rr < 2; rr++) {
                int r = wave * 32 + rr * 16 + l16;
                a[rr] = *(v8s*)&AsF[r * 64 + s * 8];
            }
#pragma unroll
            for (int c = 0; c < 8; c++) {
                int n = c * 16 + l16;
                b[c] = *(v8s*)&BsF[n * 64 + s * 8];
            }
#pragma unroll
            for (int rr = 0; rr < 2; rr++)
#pragma unroll
                for (int c = 0; c < 8; c++)
                    acc[rr][c] = __builtin_amdgcn_mfma_f32_16x16x32_bf16(a[rr], b[c], acc[rr][c], 0, 0, 0);
        }
        __syncthreads();
    }
    // store z (bf16)
#pragma unroll
    for (int rr = 0; rr < 2; rr++)
#pragma unroll
        for (int c = 0; c < 8; c++)
#pragma unroll
            for (int i = 0; i < 4; i++) {
                int row = bm + wave * 32 + rr * 16 + quad * 4 + i;
                int col = bn + c * 16 + l16;
                C[(size_t)row * N + col] = __float2bfloat16(acc[rr][c][i]);
            }
    // epilogue: el (and er for ww heads) via per-lane dot + 16-lane shuffle reduce
    const float* alp = isww ? al0 : al1;
    float* elp = isww ? el0 : el1;
    float* erp = isww ? er0 : nullptr;
    float alv[8], arv[8];
#pragma unroll
    for (int c = 0; c < 8; c++) {
        alv[c] = alp[hh * 128 + c * 16 + l16];
        arv[c] = isww ? ar0[hh * 128 + c * 16 + l16] : 0.f;
    }
#pragma unroll
    for (int rr = 0; rr < 2; rr++)
#pragma unroll
        for (int i = 0; i < 4; i++) {
            float pl = 0.f, pr = 0.f;
#pragma unroll
            for (int c = 0; c < 8; c++) {
                pl += acc[rr][c][i] * alv[c];
                pr += acc[rr][c][i] * arv[c];
            }
#pragma unroll
            for (int off = 1; off < 16; off <<= 1) {
                pl += __shfl_xor(pl, off);
                pr += __shfl_xor(pr, off);
            }
            if (l16 == 0) {
                int row = bm + wave * 32 + rr * 16 + quad * 4 + i;
                elp[(size_t)row * 4 + hh] = pl;
                if (erp) erp[(size_t)row * 4 + hh] = pr;
            }
        }
}

// ---------- CSR build ----------
__global__ void hist_k(const int* __restrict__ dst, int* __restrict__ deg, int E) {
    int t = blockIdx.x * blockDim.x + threadIdx.x;
    if (t < E) atomicAdd(&deg[dst[t]], 1);
}

// 3-phase exclusive scan: 1024 elems/block (256 thr x 4)
__global__ __launch_bounds__(256) void scan_block(const int* __restrict__ deg,
                                                  int* __restrict__ rp,
                                                  int* __restrict__ bsum, int N) {
    __shared__ int ts[256];
    int tid = threadIdx.x;
    int base = blockIdx.x * 1024 + tid * 4;
    int v0 = 0, v1 = 0, v2 = 0, v3 = 0;
    if (base + 3 < N) {
        int4 q = *(const int4*)(deg + base);
        v0 = q.x; v1 = q.y; v2 = q.z; v3 = q.w;
    } else {
        if (base + 0 < N) v0 = deg[base + 0];
        if (base + 1 < N) v1 = deg[base + 1];
        if (base + 2 < N) v2 = deg[base + 2];
        if (base + 3 < N) v3 = deg[base + 3];
    }
    int s = v0 + v1 + v2 + v3;
    ts[tid] = s;
    __syncthreads();
    for (int off = 1; off < 256; off <<= 1) {
        int t = (tid >= off) ? ts[tid - off] : 0;
        __syncthreads();
        ts[tid] += t;
        __syncthreads();
    }
    int excl = ts[tid] - s;
    if (tid == 255) bsum[blockIdx.x] = ts[255];
    if (base + 0 < N) rp[base + 0] = excl;
    if (base + 1 < N) rp[base + 1] = excl + v0;
    if (base + 2 < N) rp[base + 2] = excl + v0 + v1;
    if (base + 3 < N) rp[base + 3] = excl + v0 + v1 + v2;
}

__global__ __launch_bounds__(256) void scan_bsum(int* __restrict__ bsum, int nb) {
    __shared__ int ts[256];
    int tid = threadIdx.x;
    int v = (tid < nb) ? bsum[tid] : 0;
    ts[tid] = v;
    __syncthreads();
    for (int off = 1; off < 256; off <<= 1) {
        int t = (tid >= off) ? ts[tid - off] : 0;
        __syncthreads();
        ts[tid] += t;
        __syncthreads();
    }
    if (tid < nb) bsum[tid] = ts[tid] - v;
}

__global__ __launch_bounds__(256) void add_off(int* __restrict__ rp,
                                               const int* __restrict__ bsum,
                                               int N, int E) {
    int tid = threadIdx.x;
    int base = blockIdx.x * 1024 + tid * 4;
    int o = bsum[blockIdx.x];
    if (base + 3 < N) {
        int4 q = *(const int4*)(rp + base);
        q.x += o; q.y += o; q.z += o; q.w += o;
        *(int4*)(rp + base) = q;
    } else {
        if (base + 0 < N) rp[base + 0] += o;
        if (base + 1 < N) rp[base + 1] += o;
        if (base + 2 < N) rp[base + 2] += o;
        if (base + 3 < N) rp[base + 3] += o;
    }
    if (blockIdx.x == 0 && tid == 0) rp[N] = E;
}

__global__ void scatter_edges(const int* __restrict__ src, const int* __restrict__ dst,
                              const int* __restrict__ rp, int* __restrict__ cnt,
                              int* __restrict__ ss, int E) {
    int t = blockIdx.x * blockDim.x + threadIdx.x;
    if (t >= E) return;
    int d = dst[t];
    int pos = rp[d] + atomicAdd(&cnt[d], 1);
    ss[pos] = src[t];
}

// ---------- fused edge-softmax + aggregate: one wave per dst ----------
// Online softmax per (dst,head): running max m, denom l, rescaled accumulators.
// Algebraically identical to segment max-sub softmax.  Bias+relu fused.
__global__ __launch_bounds__(256) void softmax_agg(const int* __restrict__ rp,
                                                   const int* __restrict__ ss,
                                                   const float* __restrict__ el,
                                                   const float* __restrict__ er,
                                                   const __hip_bfloat16* __restrict__ z,
                                                   int zoff,
                                                   const float* __restrict__ b,
                                                   float* __restrict__ outf,
                                                   __hip_bfloat16* __restrict__ outb,
                                                   int Nd) {
    int wave = threadIdx.x >> 6, lane = threadIdx.x & 63;
    int d = blockIdx.x * 4 + wave;
    if (d >= Nd) return;
    int i0 = rp[d], i1 = rp[d + 1];
    float4 erd = *(const float4*)(er + (size_t)d * 4);
    float m[4], l[4], accx[4], accy[4];
#pragma unroll
    for (int h = 0; h < 4; h++) { m[h] = -FLT_MAX; l[h] = 0.f; accx[h] = 0.f; accy[h] = 0.f; }
    for (int i = i0; i < i1; i++) {
        int s = ss[i];
        float4 e4 = *(const float4*)(el + (size_t)s * 4);
        float e[4] = {e4.x + erd.x, e4.y + erd.y, e4.z + erd.z, e4.w + erd.w};
        const unsigned* zr = (const unsigned*)(z + (size_t)s * 1024 + zoff);
        unsigned u[4] = {zr[lane], zr[64 + lane], zr[128 + lane], zr[192 + lane]};
#pragma unroll
        for (int h = 0; h < 4; h++) {
            float eh = e[h] > 0.f ? e[h] : 0.2f * e[h];   // leaky_relu(0.2)
            float nm = fmaxf(m[h], eh);
            float sc = __expf(m[h] - nm);
            float p  = __expf(eh - nm);
            m[h] = nm;
            l[h] = l[h] * sc + p;
            accx[h] = accx[h] * sc + p * blo(u[h]);
            accy[h] = accy[h] * sc + p * bhi(u[h]);
        }
    }
    int f = lane * 2;
    float ax = b[f] + b[128 + f] + b[256 + f] + b[384 + f];
    float ay = b[f + 1] + b[129 + f] + b[257 + f] + b[385 + f];
#pragma unroll
    for (int h = 0; h < 4; h++) {
        float inv = l[h] > 0.f ? 1.f / l[h] : 0.f;
        ax += accx[h] * inv;
        ay += accy[h] * inv;
    }
    ax = fmaxf(ax, 0.f);
    ay = fmaxf(ay, 0.f);
    if (outf) {
        *(float2*)(outf + (size_t)d * 128 + f) = make_float2(ax, ay);
    } else {
        __hip_bfloat162 p2;
        p2.x = __float2bfloat16(ax);
        p2.y = __float2bfloat16(ay);
        *(__hip_bfloat162*)(outb + (size_t)d * 128 + f) = p2;
    }
}

static inline char* aln(char*& p, size_t bytes) {
    char* r = p;
    p += (bytes + 255) & ~(size_t)255;
    return r;
}

static void build_csr(const int* src, const int* dst, int Nd, int E,
                      int* rp, int* deg, int* bsum, int* ss, hipStream_t stream) {
    hipMemsetAsync(deg, 0, (size_t)Nd * 2 * 4, stream);
    hist_k<<<(E + 255) / 256, 256, 0, stream>>>(dst, deg, E);
    int nb = (Nd + 1023) / 1024;
    scan_block<<<nb, 256, 0, stream>>>(deg, rp, bsum, Nd);
    scan_bsum<<<1, 256, 0, stream>>>(bsum, nb);
    add_off<<<nb, 256, 0, stream>>>(rp, bsum, Nd, E);
    scatter_edges<<<(E + 255) / 256, 256, 0, stream>>>(src, dst, rp, deg + Nd, ss, E);
}

extern "C" void kernel_launch(void* const* d_in, const int* in_sizes, int n_in,
                              void* d_out, int out_size, void* d_ws, size_t ws_size,
                              hipStream_t stream) {
    const float* xw     = (const float*)d_in[0];
    const float* xd     = (const float*)d_in[1];
    const float* W_ww0  = (const float*)d_in[2];
    const float* al_ww0 = (const float*)d_in[3];
    const float* ar_ww0 = (const float*)d_in[4];
    const float* b_ww0  = (const float*)d_in[5];
    const float* W_wd0  = (const float*)d_in[6];
    const float* al_wd0 = (const float*)d_in[7];
    const float* ar_wd0 = (const float*)d_in[8];
    const float* b_wd0  = (const float*)d_in[9];
    const float* W_ww1  = (const float*)d_in[10];
    const float* al_ww1 = (const float*)d_in[11];
    const float* ar_ww1 = (const float*)d_in[12];
    const float* b_ww1  = (const float*)d_in[13];
    const float* W_wd1  = (const float*)d_in[14];
    const float* al_wd1 = (const float*)d_in[15];
    const float* ar_wd1 = (const float*)d_in[16];
    const float* b_wd1  = (const float*)d_in[17];
    const int* ww_src   = (const int*)d_in[18];
    const int* ww_dst   = (const int*)d_in[19];
    const int* wd_src   = (const int*)d_in[20];
    const int* wd_dst   = (const int*)d_in[21];

    // ---- workspace carve ----
    char* p = (char*)d_ws;
    __hip_bfloat16* z    = (__hip_bfloat16*)aln(p, (size_t)NW * 1024 * 2);  // 164 MB
    __hip_bfloat16* xwb  = (__hip_bfloat16*)aln(p, (size_t)NW * 256 * 2);
    __hip_bfloat16* xw1b = (__hip_bfloat16*)aln(p, (size_t)NW * 128 * 2);
    __hip_bfloat16* xd1b = (__hip_bfloat16*)aln(p, (size_t)ND * 128 * 2);
    __hip_bfloat16* Wt   = (__hip_bfloat16*)aln(p, (size_t)1024 * 256 * 2);
    float* el0  = (float*)aln(p, (size_t)NW * 4 * 4);   // ww src logits
    float* er0  = (float*)aln(p, (size_t)NW * 4 * 4);   // ww dst logits
    float* el1  = (float*)aln(p, (size_t)NW * 4 * 4);   // wd src logits (word rows)
    float* er1  = (float*)aln(p, (size_t)ND * 4 * 4);   // wd dst logits (doc rows)
    float* Wr   = (float*)aln(p, 4096);
    // CSR ww
    int* rp_ww  = (int*)aln(p, (size_t)(NW + 1) * 4);
    int* deg_ww = (int*)aln(p, (size_t)NW * 2 * 4);   // deg + cnt, one memset
    int* ss_ww  = (int*)aln(p, (size_t)EWW * 4);
    // CSR wd
    int* rp_wd  = (int*)aln(p, (size_t)(ND + 1) * 4);
    int* deg_wd = (int*)aln(p, (size_t)ND * 2 * 4);
    int* ss_wd  = (int*)aln(p, (size_t)EWD * 4);
    int* bsum   = (int*)aln(p, 1024);

    float* out_xw = (float*)d_out;
    float* out_xd = out_xw + (size_t)NW * 128;

    // ---- cast input features ----
    cast_bf16_v4<<<(NW * 256 / 4 + 255) / 256, 256, 0, stream>>>(
        (const float4*)xw, (uint2*)xwb, NW * 256 / 4);

    // ---- CSR build (once per graph, reused by both layers) ----
    build_csr(ww_src, ww_dst, NW, EWW, rp_ww, deg_ww, bsum, ss_ww, stream);
    build_csr(wd_src, wd_dst, ND, EWD, rp_wd, deg_wd, bsum, ss_wd, stream);

    // ================= layer 0 (K=256) =================
    transpose_w2<<<(1024 * 256 + 255) / 256, 256, 0, stream>>>(W_ww0, W_wd0, Wt, 256);
    gemm_epi<<<dim3(8, NW / 128), 256, 0, stream>>>(xwb, Wt, z, al_ww0, ar_ww0, al_wd0,
                                                    el0, er0, el1, NW, 256);
    make_wr<<<(256 * 4 + 255) / 256, 256, 0, stream>>>(W_wd0, ar_wd0, Wr, 256);
    attn_f32<<<(ND + 3) / 4, 256, 0, stream>>>(xd, Wr, er1, ND, 256);
    softmax_agg<<<(NW + 3) / 4, 256, 0, stream>>>(rp_ww, ss_ww, el0, er0, z, 0,
                                                  b_ww0, nullptr, xw1b, NW);
    softmax_agg<<<(ND + 3) / 4, 256, 0, stream>>>(rp_wd, ss_wd, el1, er1, z, 512,
                                                  b_wd0, nullptr, xd1b, ND);

    // ================= layer 1 (K=128) =================
    transpose_w2<<<(1024 * 128 + 255) / 256, 256, 0, stream>>>(W_ww1, W_wd1, Wt, 128);
    gemm_epi<<<dim3(8, NW / 128), 256, 0, stream>>>(xw1b, Wt, z, al_ww1, ar_ww1, al_wd1,
                                                    el0, er0, el1, NW, 128);
    make_wr<<<(128 * 4 + 255) / 256, 256, 0, stream>>>(W_wd1, ar_wd1, Wr, 128);
    attn_bf16<<<(ND + 3) / 4, 256, 0, stream>>>(xd1b, Wr, er1, ND, 128);
    softmax_agg<<<(NW + 3) / 4, 256, 0, stream>>>(rp_ww, ss_ww, el0, er0, z, 0,
                                                  b_ww1, out_xw, nullptr, NW);
    softmax_agg<<<(ND + 3) / 4, 256, 0, stream>>>(rp_wd, ss_wd, el1, er1, z, 512,
                                                  b_wd1, out_xd, nullptr, ND);
}

// Round 7
// 630.809 us; speedup vs baseline: 3.6977x; 1.0153x over previous
//
#include <hip/hip_runtime.h>
#include <hip/hip_bf16.h>
#include <cstddef>
#include <cfloat>

#define NW 80000
#define ND 16000
#define EWW 200000
#define EWD 200000

typedef short v8s __attribute__((ext_vector_type(8)));
typedef float v4f __attribute__((ext_vector_type(4)));

static __device__ __forceinline__ float blo(unsigned u) { return __uint_as_float(u << 16); }
static __device__ __forceinline__ float bhi(unsigned u) { return __uint_as_float(u & 0xffff0000u); }

// async global->LDS 16B copy: lane i of the wave writes lds_base + i*16
static __device__ __forceinline__ void gl2lds16(const void* g, void* l) {
    __builtin_amdgcn_global_load_lds((__attribute__((address_space(1))) void*)g,
                                     (__attribute__((address_space(3))) void*)l, 16, 0, 0);
}

// ---------- fp32 -> bf16 cast, x4 vectorized ----------
__global__ void cast_bf16_v4(const float4* __restrict__ x, uint2* __restrict__ xb, int n4) {
    int i = blockIdx.x * blockDim.x + threadIdx.x;
    if (i >= n4) return;
    float4 v = x[i];
    __hip_bfloat162 a, b;
    a.x = __float2bfloat16(v.x); a.y = __float2bfloat16(v.y);
    b.x = __float2bfloat16(v.z); b.y = __float2bfloat16(v.w);
    uint2 o;
    o.x = *(unsigned*)&a; o.y = *(unsigned*)&b;
    xb[i] = o;
}

// ---------- [Wa | Wb] ([K,512] each) -> Wt[1024,K] bf16 ----------
__global__ void transpose_w2(const float* __restrict__ Wa, const float* __restrict__ Wb,
                             __hip_bfloat16* __restrict__ Wt, int K) {
    int i = blockIdx.x * blockDim.x + threadIdx.x;
    if (i >= 1024 * K) return;
    int n = i / K, k = i - n * K;
    float v = (n < 512) ? Wa[k * 512 + n] : Wb[k * 512 + (n - 512)];
    Wt[i] = __float2bfloat16(v);
}

// ---------- Wr = per-head contraction of W with ar: [K,4] (dst side of wd) ----------
__global__ void make_wr(const float* __restrict__ W, const float* __restrict__ ar,
                        float* __restrict__ Wr, int K) {
    int i = blockIdx.x * blockDim.x + threadIdx.x;
    if (i >= K * 4) return;
    int k = i >> 2, h = i & 3;
    float sr = 0.f;
    const float* wr = W + (size_t)k * 512 + h * 128;
    const float* arr = ar + h * 128;
    for (int f = 0; f < 128; f++) sr += wr[f] * arr[f];
    Wr[k * 4 + h] = sr;
}

// ---------- er = x @ Wr ([N,4]); one wave per row; fp32 x ----------
__global__ __launch_bounds__(256) void attn_f32(const float* __restrict__ x,
                                                const float* __restrict__ Wv,
                                                float* __restrict__ out, int N, int K) {
    int wave = threadIdx.x >> 6, lane = threadIdx.x & 63;
    int row = blockIdx.x * 4 + wave;
    if (row >= N) return;
    const float* xr = x + (size_t)row * K;
    float a0 = 0.f, a1 = 0.f, a2 = 0.f, a3 = 0.f;
    for (int k = lane; k < K; k += 64) {
        float v = xr[k];
        const float* w = Wv + k * 4;
        a0 += v * w[0]; a1 += v * w[1]; a2 += v * w[2]; a3 += v * w[3];
    }
#pragma unroll
    for (int off = 32; off; off >>= 1) {
        a0 += __shfl_down(a0, off); a1 += __shfl_down(a1, off);
        a2 += __shfl_down(a2, off); a3 += __shfl_down(a3, off);
    }
    if (lane == 0) {
        out[row * 4 + 0] = a0; out[row * 4 + 1] = a1;
        out[row * 4 + 2] = a2; out[row * 4 + 3] = a3;
    }
}

// ---------- bf16-x variant ----------
__global__ __launch_bounds__(256) void attn_bf16(const __hip_bfloat16* __restrict__ x,
                                                 const float* __restrict__ Wv,
                                                 float* __restrict__ out, int N, int K) {
    int wave = threadIdx.x >> 6, lane = threadIdx.x & 63;
    int row = blockIdx.x * 4 + wave;
    if (row >= N) return;
    const __hip_bfloat16* xr = x + (size_t)row * K;
    float a0 = 0.f, a1 = 0.f, a2 = 0.f, a3 = 0.f;
    for (int k = lane; k < K; k += 64) {
        float v = __bfloat162float(xr[k]);
        const float* w = Wv + k * 4;
        a0 += v * w[0]; a1 += v * w[1]; a2 += v * w[2]; a3 += v * w[3];
    }
#pragma unroll
    for (int off = 32; off; off >>= 1) {
        a0 += __shfl_down(a0, off); a1 += __shfl_down(a1, off);
        a2 += __shfl_down(a2, off); a3 += __shfl_down(a3, off);
    }
    if (lane == 0) {
        out[row * 4 + 0] = a0; out[row * 4 + 1] = a1;
        out[row * 4 + 2] = a2; out[row * 4 + 3] = a3;
    }
}

// ---------- merged bf16 MFMA GEMM (both relations) + attention-logit epilogue ----------
// z[M,1024] = A[M,K] @ [W_ww | W_wd]  (Bt = concat^T [1024,K]).  BM=128, BK=64.
// 1-D grid, XCD-swizzled: super-tile of 64 blocks = 8 m-tiles x 8 heads laid out so
// the 8 head-blocks of one m-tile have ids differing by multiples of 8 -> same XCD
// (blocks round-robin XCDs by id%8) -> A-tile fetched once per XCD L2, hit 7x.
__global__ __launch_bounds__(256) void gemm_epi(const __hip_bfloat16* __restrict__ A,
                                                const __hip_bfloat16* __restrict__ Bt,
                                                __hip_bfloat16* __restrict__ C,
                                                const float* __restrict__ al0,
                                                const float* __restrict__ ar0,
                                                const float* __restrict__ al1,
                                                float* __restrict__ el0,
                                                float* __restrict__ er0,
                                                float* __restrict__ el1,
                                                int M, int K) {
    const int N = 1024;
    __shared__ short AsF[128 * 64];   // 16 KB, row stride 64 shorts
    __shared__ short BsF[128 * 64];
    int tid = threadIdx.x;
    int wave = tid >> 6, lane = tid & 63;
    int l16 = lane & 15, quad = lane >> 4;

    // ---- XCD swizzle ----
    int MT = M >> 7;              // number of 128-row m-tiles
    int full = MT >> 3;           // full 8-m-tile super-groups
    int bid = blockIdx.x;
    int h, mt;
    if (bid < (full << 6)) {
        int s = bid >> 6, r = bid & 63;
        h = r >> 3;
        mt = (s << 3) | (r & 7);
    } else {
        int r2 = bid - (full << 6);
        int rem = MT - (full << 3);
        h = r2 / rem;
        mt = (full << 3) + (r2 - h * rem);
    }
    bool isww = h < 4;
    int hh = isww ? h : h - 4;
    int bm = mt * 128, bn = h * 128;
    v4f acc[2][8] = {};

    int laneR = lane >> 3;                 // 0..7
    int laneC = (lane & 7) ^ laneR;        // swizzled 16B-chunk index
    const __hip_bfloat16* ga = A  + (size_t)(bm + wave * 32 + laneR) * K + laneC * 8;
    const __hip_bfloat16* gb = Bt + (size_t)(bn + wave * 32 + laneR) * K + laneC * 8;
    short* la = &AsF[(wave * 32) * 64];
    short* lb = &BsF[(wave * 32) * 64];

    for (int k0 = 0; k0 < K; k0 += 64) {
#pragma unroll
        for (int j = 0; j < 4; j++) {
            gl2lds16(ga + (size_t)(j * 8) * K + k0, la + j * 512);
            gl2lds16(gb + (size_t)(j * 8) * K + k0, lb + j * 512);
        }
        __syncthreads();
#pragma unroll
        for (int kh = 0; kh < 2; kh++) {
            int s = (kh * 4 + quad) ^ (l16 & 7);
            v8s a[2], b[8];
#pragma unroll
            for (int rr = 0; rr < 2; rr++) {
                int r = wave * 32 + rr * 16 + l16;
                a[rr] = *(v8s*)&AsF[r * 64 + s * 8];
            }
#pragma unroll
            for (int c = 0; c < 8; c++) {
                int n = c * 16 + l16;
                b[c] = *(v8s*)&BsF[n * 64 + s * 8];
            }
#pragma unroll
            for (int rr = 0; rr < 2; rr++)
#pragma unroll
                for (int c = 0; c < 8; c++)
                    acc[rr][c] = __builtin_amdgcn_mfma_f32_16x16x32_bf16(a[rr], b[c], acc[rr][c], 0, 0, 0);
        }
        __syncthreads();
    }
    // store z (bf16)
#pragma unroll
    for (int rr = 0; rr < 2; rr++)
#pragma unroll
        for (int c = 0; c < 8; c++)
#pragma unroll
            for (int i = 0; i < 4; i++) {
                int row = bm + wave * 32 + rr * 16 + quad * 4 + i;
                int col = bn + c * 16 + l16;
                C[(size_t)row * N + col] = __float2bfloat16(acc[rr][c][i]);
            }
    // epilogue: el (and er for ww heads) via per-lane dot + 16-lane shuffle reduce
    const float* alp = isww ? al0 : al1;
    float* elp = isww ? el0 : el1;
    float* erp = isww ? er0 : nullptr;
    float alv[8], arv[8];
#pragma unroll
    for (int c = 0; c < 8; c++) {
        alv[c] = alp[hh * 128 + c * 16 + l16];
        arv[c] = isww ? ar0[hh * 128 + c * 16 + l16] : 0.f;
    }
#pragma unroll
    for (int rr = 0; rr < 2; rr++)
#pragma unroll
        for (int i = 0; i < 4; i++) {
            float pl = 0.f, pr = 0.f;
#pragma unroll
            for (int c = 0; c < 8; c++) {
                pl += acc[rr][c][i] * alv[c];
                pr += acc[rr][c][i] * arv[c];
            }
#pragma unroll
            for (int off = 1; off < 16; off <<= 1) {
                pl += __shfl_xor(pl, off);
                pr += __shfl_xor(pr, off);
            }
            if (l16 == 0) {
                int row = bm + wave * 32 + rr * 16 + quad * 4 + i;
                elp[(size_t)row * 4 + hh] = pl;
                if (erp) erp[(size_t)row * 4 + hh] = pr;
            }
        }
}

// ---------- CSR build ----------
__global__ void hist_k(const int* __restrict__ dst, int* __restrict__ deg, int E) {
    int t = blockIdx.x * blockDim.x + threadIdx.x;
    if (t < E) atomicAdd(&deg[dst[t]], 1);
}

// 3-phase exclusive scan: 1024 elems/block (256 thr x 4)
__global__ __launch_bounds__(256) void scan_block(const int* __restrict__ deg,
                                                  int* __restrict__ rp,
                                                  int* __restrict__ bsum, int N) {
    __shared__ int ts[256];
    int tid = threadIdx.x;
    int base = blockIdx.x * 1024 + tid * 4;
    int v0 = 0, v1 = 0, v2 = 0, v3 = 0;
    if (base + 3 < N) {
        int4 q = *(const int4*)(deg + base);
        v0 = q.x; v1 = q.y; v2 = q.z; v3 = q.w;
    } else {
        if (base + 0 < N) v0 = deg[base + 0];
        if (base + 1 < N) v1 = deg[base + 1];
        if (base + 2 < N) v2 = deg[base + 2];
        if (base + 3 < N) v3 = deg[base + 3];
    }
    int s = v0 + v1 + v2 + v3;
    ts[tid] = s;
    __syncthreads();
    for (int off = 1; off < 256; off <<= 1) {
        int t = (tid >= off) ? ts[tid - off] : 0;
        __syncthreads();
        ts[tid] += t;
        __syncthreads();
    }
    int excl = ts[tid] - s;
    if (tid == 255) bsum[blockIdx.x] = ts[255];
    if (base + 0 < N) rp[base + 0] = excl;
    if (base + 1 < N) rp[base + 1] = excl + v0;
    if (base + 2 < N) rp[base + 2] = excl + v0 + v1;
    if (base + 3 < N) rp[base + 3] = excl + v0 + v1 + v2;
}

__global__ __launch_bounds__(256) void scan_bsum(int* __restrict__ bsum, int nb) {
    __shared__ int ts[256];
    int tid = threadIdx.x;
    int v = (tid < nb) ? bsum[tid] : 0;
    ts[tid] = v;
    __syncthreads();
    for (int off = 1; off < 256; off <<= 1) {
        int t = (tid >= off) ? ts[tid - off] : 0;
        __syncthreads();
        ts[tid] += t;
        __syncthreads();
    }
    if (tid < nb) bsum[tid] = ts[tid] - v;
}

__global__ __launch_bounds__(256) void add_off(int* __restrict__ rp,
                                               const int* __restrict__ bsum,
                                               int N, int E) {
    int tid = threadIdx.x;
    int base = blockIdx.x * 1024 + tid * 4;
    int o = bsum[blockIdx.x];
    if (base + 3 < N) {
        int4 q = *(const int4*)(rp + base);
        q.x += o; q.y += o; q.z += o; q.w += o;
        *(int4*)(rp + base) = q;
    } else {
        if (base + 0 < N) rp[base + 0] += o;
        if (base + 1 < N) rp[base + 1] += o;
        if (base + 2 < N) rp[base + 2] += o;
        if (base + 3 < N) rp[base + 3] += o;
    }
    if (blockIdx.x == 0 && tid == 0) rp[N] = E;
}

__global__ void scatter_edges(const int* __restrict__ src, const int* __restrict__ dst,
                              const int* __restrict__ rp, int* __restrict__ cnt,
                              int* __restrict__ ss, int E) {
    int t = blockIdx.x * blockDim.x + threadIdx.x;
    if (t >= E) return;
    int d = dst[t];
    int pos = rp[d] + atomicAdd(&cnt[d], 1);
    ss[pos] = src[t];
}

// ---------- fused edge-softmax + aggregate: one wave per dst ----------
// Online softmax per (dst,head); ss[i+1] prefetched one iteration ahead so the
// two-level load chain (ss -> el,z) overlaps the previous edge's accumulation.
__global__ __launch_bounds__(256) void softmax_agg(const int* __restrict__ rp,
                                                   const int* __restrict__ ss,
                                                   const float* __restrict__ el,
                                                   const float* __restrict__ er,
                                                   const __hip_bfloat16* __restrict__ z,
                                                   int zoff,
                                                   const float* __restrict__ b,
                                                   float* __restrict__ outf,
                                                   __hip_bfloat16* __restrict__ outb,
                                                   int Nd) {
    int wave = threadIdx.x >> 6, lane = threadIdx.x & 63;
    int d = blockIdx.x * 4 + wave;
    if (d >= Nd) return;
    int i0 = rp[d], i1 = rp[d + 1];
    float4 erd = *(const float4*)(er + (size_t)d * 4);
    float m[4], l[4], accx[4], accy[4];
#pragma unroll
    for (int h = 0; h < 4; h++) { m[h] = -FLT_MAX; l[h] = 0.f; accx[h] = 0.f; accy[h] = 0.f; }
    int sA = (i0 < i1) ? ss[i0] : 0;
    for (int i = i0; i < i1; i++) {
        int sB = (i + 1 < i1) ? ss[i + 1] : 0;   // prefetch next src index
        float4 e4 = *(const float4*)(el + (size_t)sA * 4);
        const unsigned* zr = (const unsigned*)(z + (size_t)sA * 1024 + zoff);
        unsigned u[4] = {zr[lane], zr[64 + lane], zr[128 + lane], zr[192 + lane]};
        float e[4] = {e4.x + erd.x, e4.y + erd.y, e4.z + erd.z, e4.w + erd.w};
#pragma unroll
        for (int h = 0; h < 4; h++) {
            float eh = e[h] > 0.f ? e[h] : 0.2f * e[h];   // leaky_relu(0.2)
            float nm = fmaxf(m[h], eh);
            float sc = __expf(m[h] - nm);
            float p  = __expf(eh - nm);
            m[h] = nm;
            l[h] = l[h] * sc + p;
            accx[h] = accx[h] * sc + p * blo(u[h]);
            accy[h] = accy[h] * sc + p * bhi(u[h]);
        }
        sA = sB;
    }
    int f = lane * 2;
    float ax = b[f] + b[128 + f] + b[256 + f] + b[384 + f];
    float ay = b[f + 1] + b[129 + f] + b[257 + f] + b[385 + f];
#pragma unroll
    for (int h = 0; h < 4; h++) {
        float inv = l[h] > 0.f ? 1.f / l[h] : 0.f;
        ax += accx[h] * inv;
        ay += accy[h] * inv;
    }
    ax = fmaxf(ax, 0.f);
    ay = fmaxf(ay, 0.f);
    if (outf) {
        *(float2*)(outf + (size_t)d * 128 + f) = make_float2(ax, ay);
    } else {
        __hip_bfloat162 p2;
        p2.x = __float2bfloat16(ax);
        p2.y = __float2bfloat16(ay);
        *(__hip_bfloat162*)(outb + (size_t)d * 128 + f) = p2;
    }
}

static inline char* aln(char*& p, size_t bytes) {
    char* r = p;
    p += (bytes + 255) & ~(size_t)255;
    return r;
}

static void build_csr(const int* src, const int* dst, int Nd, int E,
                      int* rp, int* deg, int* bsum, int* ss, hipStream_t stream) {
    hipMemsetAsync(deg, 0, (size_t)Nd * 2 * 4, stream);
    hist_k<<<(E + 255) / 256, 256, 0, stream>>>(dst, deg, E);
    int nb = (Nd + 1023) / 1024;
    scan_block<<<nb, 256, 0, stream>>>(deg, rp, bsum, Nd);
    scan_bsum<<<1, 256, 0, stream>>>(bsum, nb);
    add_off<<<nb, 256, 0, stream>>>(rp, bsum, Nd, E);
    scatter_edges<<<(E + 255) / 256, 256, 0, stream>>>(src, dst, rp, deg + Nd, ss, E);
}

extern "C" void kernel_launch(void* const* d_in, const int* in_sizes, int n_in,
                              void* d_out, int out_size, void* d_ws, size_t ws_size,
                              hipStream_t stream) {
    const float* xw     = (const float*)d_in[0];
    const float* xd     = (const float*)d_in[1];
    const float* W_ww0  = (const float*)d_in[2];
    const float* al_ww0 = (const float*)d_in[3];
    const float* ar_ww0 = (const float*)d_in[4];
    const float* b_ww0  = (const float*)d_in[5];
    const float* W_wd0  = (const float*)d_in[6];
    const float* al_wd0 = (const float*)d_in[7];
    const float* ar_wd0 = (const float*)d_in[8];
    const float* b_wd0  = (const float*)d_in[9];
    const float* W_ww1  = (const float*)d_in[10];
    const float* al_ww1 = (const float*)d_in[11];
    const float* ar_ww1 = (const float*)d_in[12];
    const float* b_ww1  = (const float*)d_in[13];
    const float* W_wd1  = (const float*)d_in[14];
    const float* al_wd1 = (const float*)d_in[15];
    const float* ar_wd1 = (const float*)d_in[16];
    const float* b_wd1  = (const float*)d_in[17];
    const int* ww_src   = (const int*)d_in[18];
    const int* ww_dst   = (const int*)d_in[19];
    const int* wd_src   = (const int*)d_in[20];
    const int* wd_dst   = (const int*)d_in[21];

    // ---- workspace carve ----
    char* p = (char*)d_ws;
    __hip_bfloat16* z    = (__hip_bfloat16*)aln(p, (size_t)NW * 1024 * 2);  // 164 MB
    __hip_bfloat16* xwb  = (__hip_bfloat16*)aln(p, (size_t)NW * 256 * 2);
    __hip_bfloat16* xw1b = (__hip_bfloat16*)aln(p, (size_t)NW * 128 * 2);
    __hip_bfloat16* xd1b = (__hip_bfloat16*)aln(p, (size_t)ND * 128 * 2);
    __hip_bfloat16* Wt   = (__hip_bfloat16*)aln(p, (size_t)1024 * 256 * 2);
    float* el0  = (float*)aln(p, (size_t)NW * 4 * 4);   // ww src logits
    float* er0  = (float*)aln(p, (size_t)NW * 4 * 4);   // ww dst logits
    float* el1  = (float*)aln(p, (size_t)NW * 4 * 4);   // wd src logits (word rows)
    float* er1  = (float*)aln(p, (size_t)ND * 4 * 4);   // wd dst logits (doc rows)
    float* Wr   = (float*)aln(p, 4096);
    // CSR ww
    int* rp_ww  = (int*)aln(p, (size_t)(NW + 1) * 4);
    int* deg_ww = (int*)aln(p, (size_t)NW * 2 * 4);   // deg + cnt, one memset
    int* ss_ww  = (int*)aln(p, (size_t)EWW * 4);
    // CSR wd
    int* rp_wd  = (int*)aln(p, (size_t)(ND + 1) * 4);
    int* deg_wd = (int*)aln(p, (size_t)ND * 2 * 4);
    int* ss_wd  = (int*)aln(p, (size_t)EWD * 4);
    int* bsum   = (int*)aln(p, 1024);

    float* out_xw = (float*)d_out;
    float* out_xd = out_xw + (size_t)NW * 128;

    // ---- cast input features ----
    cast_bf16_v4<<<(NW * 256 / 4 + 255) / 256, 256, 0, stream>>>(
        (const float4*)xw, (uint2*)xwb, NW * 256 / 4);

    // ---- CSR build (once per graph, reused by both layers) ----
    build_csr(ww_src, ww_dst, NW, EWW, rp_ww, deg_ww, bsum, ss_ww, stream);
    build_csr(wd_src, wd_dst, ND, EWD, rp_wd, deg_wd, bsum, ss_wd, stream);

    const int GEMM_BLOCKS = 8 * (NW / 128);   // 5000

    // ================= layer 0 (K=256) =================
    transpose_w2<<<(1024 * 256 + 255) / 256, 256, 0, stream>>>(W_ww0, W_wd0, Wt, 256);
    gemm_epi<<<GEMM_BLOCKS, 256, 0, stream>>>(xwb, Wt, z, al_ww0, ar_ww0, al_wd0,
                                              el0, er0, el1, NW, 256);
    make_wr<<<(256 * 4 + 255) / 256, 256, 0, stream>>>(W_wd0, ar_wd0, Wr, 256);
    attn_f32<<<(ND + 3) / 4, 256, 0, stream>>>(xd, Wr, er1, ND, 256);
    softmax_agg<<<(NW + 3) / 4, 256, 0, stream>>>(rp_ww, ss_ww, el0, er0, z, 0,
                                                  b_ww0, nullptr, xw1b, NW);
    softmax_agg<<<(ND + 3) / 4, 256, 0, stream>>>(rp_wd, ss_wd, el1, er1, z, 512,
                                                  b_wd0, nullptr, xd1b, ND);

    // ================= layer 1 (K=128) =================
    transpose_w2<<<(1024 * 128 + 255) / 256, 256, 0, stream>>>(W_ww1, W_wd1, Wt, 128);
    gemm_epi<<<GEMM_BLOCKS, 256, 0, stream>>>(xw1b, Wt, z, al_ww1, ar_ww1, al_wd1,
                                              el0, er0, el1, NW, 128);
    make_wr<<<(128 * 4 + 255) / 256, 256, 0, stream>>>(W_wd1, ar_wd1, Wr, 128);
    attn_bf16<<<(ND + 3) / 4, 256, 0, stream>>>(xd1b, Wr, er1, ND, 128);
    softmax_agg<<<(NW + 3) / 4, 256, 0, stream>>>(rp_ww, ss_ww, el0, er0, z, 0,
                                                  b_ww1, out_xw, nullptr, NW);
    softmax_agg<<<(ND + 3) / 4, 256, 0, stream>>>(rp_wd, ss_wd, el1, er1, z, 512,
                                                  b_wd1, out_xd, nullptr, ND);
}